// Round 7
// baseline (840.976 us; speedup 1.0000x reference)
//
#include <hip/hip_runtime.h>

#define NNODES 50000
#define NPAD   50048   // 391 * 128
#define NEDGES 800000
#define HDIM 128
#define OUTDIM 64

#define GEMM_GRID 391
#define GEMM_BLK  512

typedef short short8 __attribute__((ext_vector_type(8)));
typedef _Float16 half8 __attribute__((ext_vector_type(8)));
typedef _Float16 half4 __attribute__((ext_vector_type(4)));
typedef float f32x4 __attribute__((ext_vector_type(4)));
typedef float f32x8 __attribute__((ext_vector_type(8)));

__device__ __forceinline__ unsigned short f2bf(float f) {
    unsigned int u = __builtin_bit_cast(unsigned int, f);
    unsigned int r = (u + 0x7FFFu + ((u >> 16) & 1u)) >> 16;
    return (unsigned short)r;
}
__device__ __forceinline__ float bf2f(unsigned short b) {
    unsigned int u = ((unsigned int)b) << 16;
    return __builtin_bit_cast(float, u);
}

// ---------------- CSR build ----------------
__global__ void count_kernel(const int* __restrict__ dst, int* __restrict__ deg,
                             int* __restrict__ epos) {
    int e = blockIdx.x * 256 + threadIdx.x;
    if (e < NEDGES) epos[e] = atomicAdd(&deg[dst[e]], 1);
}

__global__ __launch_bounds__(256) void bsum_kernel(const int* __restrict__ deg,
                                                   int* __restrict__ bsum) {
    __shared__ int red[256];
    int i = blockIdx.x * 256 + threadIdx.x;
    red[threadIdx.x] = (i < NNODES) ? deg[i] : 0;
    __syncthreads();
    for (int off = 128; off; off >>= 1) {
        if (threadIdx.x < off) red[threadIdx.x] += red[threadIdx.x + off];
        __syncthreads();
    }
    if (threadIdx.x == 0) bsum[blockIdx.x] = red[0];
}

__global__ __launch_bounds__(256) void bscan_kernel(const int* __restrict__ bsum,
                                                    int* __restrict__ bofs) {
    __shared__ int s[256];
    int t = threadIdx.x;
    int v = (t < 196) ? bsum[t] : 0;
    s[t] = v;
    __syncthreads();
    for (int off = 1; off < 256; off <<= 1) {
        int u = (t >= off) ? s[t - off] : 0;
        __syncthreads();
        s[t] += u;
        __syncthreads();
    }
    if (t < 196) bofs[t] = s[t] - v;  // exclusive
}

__global__ __launch_bounds__(256) void emit_kernel(
    const int* __restrict__ deg, const int* __restrict__ bofs,
    int* __restrict__ row_ptr, float* __restrict__ norm) {
    __shared__ int s[256];
    int t = threadIdx.x;
    int i = blockIdx.x * 256 + t;
    int v = (i < NNODES) ? deg[i] : 0;
    s[t] = v;
    __syncthreads();
    for (int off = 1; off < 256; off <<= 1) {
        int u = (t >= off) ? s[t - off] : 0;
        __syncthreads();
        s[t] += u;
        __syncthreads();
    }
    int excl = s[t] - v + bofs[blockIdx.x];
    if (i < NNODES) {
        row_ptr[i] = excl;
        norm[i] = rsqrtf(1.0f + (float)v);
    }
    if (i == NNODES - 1) row_ptr[NNODES] = NEDGES;
}

__global__ void fill_kernel(const int* __restrict__ src, const int* __restrict__ dst,
                            const int* __restrict__ epos, const int* __restrict__ row_ptr,
                            int* __restrict__ sorted_src) {
    int e = blockIdx.x * 256 + threadIdx.x;
    if (e < NEDGES) sorted_src[row_ptr[dst[e]] + epos[e]] = src[e];
}

// ---------------- weight prep ----------------
// bf16 hi/lo (wT): w_in slot 0, w1[m] slot 1+m, w_out slot 7 (64 rows).
// f16 single (w2f): w2[m] at m*16384, layout [n][128].
__global__ __launch_bounds__(256) void prep_w_kernel(
    const float* __restrict__ w_in, const float* __restrict__ w1,
    const float* __restrict__ w2, const float* __restrict__ w_out,
    unsigned short* __restrict__ wT, _Float16* __restrict__ w2f) {
    int idx = blockIdx.x * 256 + threadIdx.x;  // total 221184 = 864*256
    if (idx < 16384 + 98304) {
        const float* W;
        unsigned short* o;
        int e;
        if (idx < 16384) {
            W = w_in; o = wT; e = idx;
        } else {
            int j = idx - 16384; int m = j >> 14; e = j & 16383;
            W = w1 + ((size_t)m << 14); o = wT + (size_t)(1 + m) * 32768;
        }
        int k = e >> 7, n = e & 127;
        float v = W[e];
        unsigned short h = f2bf(v);
        o[(size_t)n * 256 + k] = h;
        o[(size_t)n * 256 + 128 + k] = f2bf(v - bf2f(h));
    } else if (idx < 16384 + 196608) {
        int j = idx - 16384 - 98304; int m = j >> 14; int e = j & 16383;
        int k = e >> 7, n = e & 127;
        w2f[(size_t)m * 16384 + n * 128 + k] = (_Float16)w2[((size_t)m << 14) + e];
    } else {
        int e = idx - 212992;  // w_out: 8192 elements
        int k = e >> 6, n = e & 63;
        float v = w_out[e];
        unsigned short h = f2bf(v);
        unsigned short* o = wT + (size_t)7 * 32768;
        o[(size_t)n * 256 + k] = h;
        o[(size_t)n * 256 + 128 + k] = f2bf(v - bf2f(h));
    }
}

// ---------------- x split (input layer only) ----------------
__global__ __launch_bounds__(256) void split_x_kernel(
    const float* __restrict__ x, unsigned short* __restrict__ xc) {
    int gid = blockIdx.x * 256 + threadIdx.x;
    int row = gid >> 6;
    int kk = (gid & 63) * 2;
    float2 v = {0.f, 0.f};
    if (row < NNODES) v = *(const float2*)(x + (size_t)row * 128 + kk);
    unsigned short h0 = f2bf(v.x), h1 = f2bf(v.y);
    unsigned short l0 = f2bf(v.x - bf2f(h0)), l1 = f2bf(v.y - bf2f(h1));
    *(unsigned int*)(xc + (size_t)row * 256 + kk) =
        (unsigned int)h0 | ((unsigned int)h1 << 16);
    *(unsigned int*)(xc + (size_t)row * 256 + 128 + kk) =
        (unsigned int)l0 | ((unsigned int)l1 << 16);
}

// ---------------- bf16 hi/lo streaming MFMA GEMM (input layer only) --------
template <int NCOLS>
__global__ __launch_bounds__(GEMM_BLK) void gemm_bf_kernel(
    const unsigned short* __restrict__ xc, const unsigned short* __restrict__ wT,
    const float* __restrict__ norm, _Float16* __restrict__ y) {
    __shared__ unsigned short Blds[NCOLS * 256];
    const int t = threadIdx.x;
    const int wave = t >> 6, lane = t & 63, quad = lane >> 4, l16 = lane & 15;

    constexpr int NCH = NCOLS * 32;  // 16B chunks total
#pragma unroll
    for (int i = 0; i < NCH / GEMM_BLK; ++i) {
        int C = i * GEMM_BLK + t;
        int n = C >> 5, c = C & 31;
        const unsigned short* gp = wT + ((size_t)n << 8) + ((c ^ (n & 7)) << 3);
        unsigned short* lp = Blds + ((size_t)C << 3);
        __builtin_amdgcn_global_load_lds(
            (const __attribute__((address_space(1))) void*)gp,
            (__attribute__((address_space(3))) void*)lp, 16, 0, 0);
    }
    __syncthreads();

    const int wid = blockIdx.x * (GEMM_BLK / 64) + wave;
    const int sw = l16 & 7;
    const int rb0 = wid * 16;

    short8 a0[8];
    const unsigned short* ap0 = xc + ((size_t)(rb0 + l16) << 8) + quad * 8;
#pragma unroll
    for (int ck = 0; ck < 8; ++ck) a0[ck] = *(const short8*)(ap0 + ck * 32);

    float nm0[4];
#pragma unroll
    for (int r = 0; r < 4; ++r) {
        int r0 = rb0 + quad * 4 + r;
        nm0[r] = norm[r0 < NNODES ? r0 : 0];
    }

#pragma unroll
    for (int nt = 0; nt < NCOLS / 16; ++nt) {
        const unsigned short* bp = Blds + ((size_t)(nt * 16 + l16) << 8);
        short8 bh[4], bl[4];
#pragma unroll
        for (int ck = 0; ck < 4; ++ck) {
            bh[ck] = *(const short8*)(bp + (((ck * 4 + quad) ^ sw) << 3));
            bl[ck] = *(const short8*)(bp + (((16 + ck * 4 + quad) ^ sw) << 3));
        }
        f32x4 ac0 = (f32x4){0.f, 0.f, 0.f, 0.f};
#pragma unroll
        for (int ck = 0; ck < 4; ++ck) {
            ac0 = __builtin_amdgcn_mfma_f32_16x16x32_bf16(a0[ck], bh[ck], ac0, 0, 0, 0);
            ac0 = __builtin_amdgcn_mfma_f32_16x16x32_bf16(a0[ck], bl[ck], ac0, 0, 0, 0);
            ac0 = __builtin_amdgcn_mfma_f32_16x16x32_bf16(a0[4 + ck], bh[ck], ac0, 0, 0, 0);
        }
        int col = nt * 16 + l16;
#pragma unroll
        for (int r = 0; r < 4; ++r) {
            int r0 = rb0 + quad * 4 + r;
            if (r0 < NNODES) y[(size_t)r0 * NCOLS + col] = (_Float16)(ac0[r] * nm0[r]);
        }
    }
}

// -------- FUSED gather+finalize + bf16 hi/lo GEMM (fgb) ---------------------
// Replaces {gather_fin -> xc write} + {gemm_bf reading xc}. Wave gathers its
// 16 rows, finalizes (leaky / +residual), writes xc_x (if WRXC) and/or fp32 x
// (if WOUT), transposes rows into wave-private LDS (8KB), then runs the hi/lo
// MFMA phase. Barrier sits right after B-stage issue: no wave waits on other
// waves' gather stragglers; fast waves' MFMA overlaps slow waves' gathers.
template <int MODE, int NCOLS, bool WOUT, bool WRXC>
__global__ __launch_bounds__(GEMM_BLK) void fgb_kernel(
    const _Float16* __restrict__ y, const int* __restrict__ row_ptr,
    const int* __restrict__ sorted_src, const float* __restrict__ norm,
    const float* __restrict__ bias, const unsigned short* __restrict__ xcres,
    const unsigned short* __restrict__ wTb, unsigned short* __restrict__ xcout,
    float* __restrict__ xfull, _Float16* __restrict__ yout) {
    __shared__ unsigned short Blds[NCOLS * 256];       // 64KB (128) / 32KB (64)
    __shared__ unsigned short Alds[8 * 16 * 256];      // 64KB, 8KB per wave
    const int t = threadIdx.x;
    const int wave = t >> 6, lane = t & 63, quad = lane >> 4, l16 = lane & 15;

    // ---- B stage, then immediate barrier (drains the global_load_lds) ----
    constexpr int NCH = NCOLS * 32;
#pragma unroll
    for (int i = 0; i < NCH / GEMM_BLK; ++i) {
        int C = i * GEMM_BLK + t;
        int n = C >> 5, c = C & 31;
        const unsigned short* gp = wTb + ((size_t)n << 8) + ((c ^ (n & 7)) << 3);
        unsigned short* lp = Blds + ((size_t)C << 3);
        __builtin_amdgcn_global_load_lds(
            (const __attribute__((address_space(1))) void*)gp,
            (__attribute__((address_space(3))) void*)lp, 16, 0, 0);
    }
    __syncthreads();

    const int wid = blockIdx.x * (GEMM_BLK / 64) + wave;
    const int rb0 = wid * 16;
    unsigned short* Aw = Alds + (size_t)wave * 4096;
    const int g = quad, j = l16;

    // ---- gather + finalize phase: 4 batches x 4 nodes, 16 lanes/node ----
    for (int tb = 0; tb < 4; ++tb) {
        const int n = rb0 + tb * 4 + g;
        const bool valid = n < NNODES;
        const int beg = valid ? row_ptr[n] : 0;
        const int dg = valid ? (row_ptr[n + 1] - beg) : 0;
        int dmax = dg;
        dmax = max(dmax, __shfl_xor(dmax, 16));
        dmax = max(dmax, __shfl_xor(dmax, 32));

        f32x8 acc = (f32x8){0.f, 0.f, 0.f, 0.f, 0.f, 0.f, 0.f, 0.f};
        for (int i = 0; i < dmax; i += 8) {
            int sarr[8];
#pragma unroll
            for (int u = 0; u < 8; ++u)
                sarr[u] = (i + u < dg) ? sorted_src[beg + i + u] : -1;
            half8 h[8];
#pragma unroll
            for (int u = 0; u < 8; ++u)
                if (sarr[u] >= 0)
                    h[u] = *(const half8*)(y + ((size_t)sarr[u] << 7) + j * 8);
#pragma unroll
            for (int u = 0; u < 8; ++u)
                if (sarr[u] >= 0) acc += __builtin_convertvector(h[u], f32x8);
        }

        short8 hi = (short8){0, 0, 0, 0, 0, 0, 0, 0};
        short8 lo = hi;
        if (valid) {
            const half8 sh = *(const half8*)(y + ((size_t)n << 7) + j * 8);
            const f32x4 b0 = *(const f32x4*)(bias + j * 8);
            const f32x4 b1 = *(const f32x4*)(bias + j * 8 + 4);
            const float bb[8] = {b0[0], b0[1], b0[2], b0[3], b1[0], b1[1], b1[2], b1[3]};
            const float nm = norm[n];
            float v[8];
#pragma unroll
            for (int c = 0; c < 8; ++c) {
                float tv = (acc[c] + (float)sh[c]) * nm + bb[c];
                v[c] = tv >= 0.f ? tv : 0.01f * tv;
            }
            if (MODE == 1) {
                short8 hw = __builtin_nontemporal_load(
                    (const short8*)(xcres + ((size_t)n << 8) + j * 8));
                short8 lw = __builtin_nontemporal_load(
                    (const short8*)(xcres + ((size_t)n << 8) + 128 + j * 8));
#pragma unroll
                for (int c = 0; c < 8; ++c) {
                    float xr = bf2f((unsigned short)hw[c]) + bf2f((unsigned short)lw[c]);
                    v[c] = (xr + v[c]) * 0.5f;
                }
            }
            if (WOUT) {
                f32x4 o0 = (f32x4){v[0], v[1], v[2], v[3]};
                f32x4 o1 = (f32x4){v[4], v[5], v[6], v[7]};
                __builtin_nontemporal_store(o0, (f32x4*)(xfull + ((size_t)n << 7) + j * 8));
                __builtin_nontemporal_store(o1, (f32x4*)(xfull + ((size_t)n << 7) + j * 8 + 4));
            }
#pragma unroll
            for (int c = 0; c < 8; ++c) {
                unsigned short hv = f2bf(v[c]);
                hi[c] = (short)hv;
                lo[c] = (short)f2bf(v[c] - bf2f(hv));
            }
            if (WRXC) {
                *(short8*)(xcout + ((size_t)n << 8) + j * 8) = hi;
                *(short8*)(xcout + ((size_t)n << 8) + 128 + j * 8) = lo;
            }
        }
        *(short8*)(Aw + (size_t)(tb * 4 + g) * 256 + j * 8) = hi;
        *(short8*)(Aw + (size_t)(tb * 4 + g) * 256 + 128 + j * 8) = lo;
    }

    // ---- MFMA phase (A wave-local LDS, B block LDS) — no barrier needed ----
    const int sw = l16 & 7;
    short8 a0[8];
#pragma unroll
    for (int ck = 0; ck < 8; ++ck)
        a0[ck] = *(const short8*)(Aw + (size_t)l16 * 256 + quad * 8 + ck * 32);

    float nm0[4];
#pragma unroll
    for (int r = 0; r < 4; ++r) {
        int r0 = rb0 + quad * 4 + r;
        nm0[r] = norm[r0 < NNODES ? r0 : 0];
    }

#pragma unroll
    for (int nt = 0; nt < NCOLS / 16; ++nt) {
        const unsigned short* bp = Blds + ((size_t)(nt * 16 + l16) << 8);
        short8 bh[4], bl[4];
#pragma unroll
        for (int ck = 0; ck < 4; ++ck) {
            bh[ck] = *(const short8*)(bp + (((ck * 4 + quad) ^ sw) << 3));
            bl[ck] = *(const short8*)(bp + (((16 + ck * 4 + quad) ^ sw) << 3));
        }
        f32x4 ac0 = (f32x4){0.f, 0.f, 0.f, 0.f};
#pragma unroll
        for (int ck = 0; ck < 4; ++ck) {
            ac0 = __builtin_amdgcn_mfma_f32_16x16x32_bf16(a0[ck], bh[ck], ac0, 0, 0, 0);
            ac0 = __builtin_amdgcn_mfma_f32_16x16x32_bf16(a0[ck], bl[ck], ac0, 0, 0, 0);
            ac0 = __builtin_amdgcn_mfma_f32_16x16x32_bf16(a0[4 + ck], bh[ck], ac0, 0, 0, 0);
        }
        int col = nt * 16 + l16;
#pragma unroll
        for (int r = 0; r < 4; ++r) {
            int r0 = rb0 + quad * 4 + r;
            if (r0 < NNODES) yout[(size_t)r0 * NCOLS + col] = (_Float16)(ac0[r] * nm0[r]);
        }
    }
}

// -------- FUSED gather+finalize+f16 GEMM (fgg) ------------------------------
__global__ __launch_bounds__(GEMM_BLK) void fgg_f16_kernel(
    const _Float16* __restrict__ y, const int* __restrict__ row_ptr,
    const int* __restrict__ sorted_src, const float* __restrict__ norm,
    const float* __restrict__ bias, const _Float16* __restrict__ wf,
    _Float16* __restrict__ yout) {
    __shared__ _Float16 Blds[128 * 128];          // 32 KB
    __shared__ _Float16 Alds[8 * 16 * 128];       // 32 KB, 4KB per wave
    const int t = threadIdx.x;
    const int wave = t >> 6, lane = t & 63, quad = lane >> 4, l16 = lane & 15;

    // ---- B stage, then immediate barrier ----
#pragma unroll
    for (int i = 0; i < 2048 / GEMM_BLK; ++i) {
        int C = i * GEMM_BLK + t;
        int n = C >> 4, c = C & 15;
        const _Float16* gp = wf + ((size_t)n << 7) + ((c ^ (n & 7)) << 3);
        _Float16* lp = Blds + ((size_t)C << 3);
        __builtin_amdgcn_global_load_lds(
            (const __attribute__((address_space(1))) void*)gp,
            (__attribute__((address_space(3))) void*)lp, 16, 0, 0);
    }
    __syncthreads();

    const int wid = blockIdx.x * (GEMM_BLK / 64) + wave;
    const int rb0 = wid * 16;
    _Float16* Aw = Alds + (size_t)wave * 2048;
    const int g = quad, j = l16;

    // ---- gather phase: 4 batches x 4 nodes/wave, 16 lanes per node ----
    for (int tb = 0; tb < 4; ++tb) {
        const int n = rb0 + tb * 4 + g;
        const bool valid = n < NNODES;
        const int beg = valid ? row_ptr[n] : 0;
        const int dg = valid ? (row_ptr[n + 1] - beg) : 0;
        int dmax = dg;
        dmax = max(dmax, __shfl_xor(dmax, 16));
        dmax = max(dmax, __shfl_xor(dmax, 32));

        f32x8 acc = (f32x8){0.f, 0.f, 0.f, 0.f, 0.f, 0.f, 0.f, 0.f};
        for (int i = 0; i < dmax; i += 8) {
            int sarr[8];
#pragma unroll
            for (int u = 0; u < 8; ++u)
                sarr[u] = (i + u < dg) ? sorted_src[beg + i + u] : -1;
            half8 h[8];
#pragma unroll
            for (int u = 0; u < 8; ++u)
                if (sarr[u] >= 0)
                    h[u] = *(const half8*)(y + ((size_t)sarr[u] << 7) + j * 8);
#pragma unroll
            for (int u = 0; u < 8; ++u)
                if (sarr[u] >= 0) acc += __builtin_convertvector(h[u], f32x8);
        }

        half8 o;
        if (valid) {
            const half8 sh = *(const half8*)(y + ((size_t)n << 7) + j * 8);
            const f32x4 b0 = *(const f32x4*)(bias + j * 8);
            const f32x4 b1 = *(const f32x4*)(bias + j * 8 + 4);
            const float bb[8] = {b0[0], b0[1], b0[2], b0[3], b1[0], b1[1], b1[2], b1[3]};
            const float nm = norm[n];
#pragma unroll
            for (int c = 0; c < 8; ++c) {
                float v = (acc[c] + (float)sh[c]) * nm + bb[c];
                v = v >= 0.f ? v : 0.01f * v;
                o[c] = (_Float16)v;
            }
        } else {
#pragma unroll
            for (int c = 0; c < 8; ++c) o[c] = (_Float16)0.f;
        }
        *(half8*)(Aw + (size_t)(tb * 4 + g) * 128 + j * 8) = o;
    }

    // ---- MFMA phase (A wave-local, B valid since barrier) ----
    const int sw = l16 & 7;
    half8 a0[4];
#pragma unroll
    for (int ck = 0; ck < 4; ++ck)
        a0[ck] = *(const half8*)(Aw + (size_t)l16 * 128 + ck * 32 + quad * 8);

    float nm0[4];
#pragma unroll
    for (int r = 0; r < 4; ++r) {
        int r0 = rb0 + quad * 4 + r;
        nm0[r] = norm[r0 < NNODES ? r0 : 0];
    }

#pragma unroll
    for (int nt = 0; nt < 8; ++nt) {
        const _Float16* bp = Blds + ((size_t)(nt * 16 + l16) << 7);
        half8 b[4];
#pragma unroll
        for (int ck = 0; ck < 4; ++ck)
            b[ck] = *(const half8*)(bp + (((ck * 4 + quad) ^ sw) << 3));
        f32x4 ac0 = (f32x4){0.f, 0.f, 0.f, 0.f};
#pragma unroll
        for (int ck = 0; ck < 4; ++ck)
            ac0 = __builtin_amdgcn_mfma_f32_16x16x32_f16(a0[ck], b[ck], ac0, 0, 0, 0);
        int col = nt * 16 + l16;
#pragma unroll
        for (int r = 0; r < 4; ++r) {
            int r0 = rb0 + quad * 4 + r;
            if (r0 < NNODES) yout[(size_t)r0 * 128 + col] = (_Float16)(ac0[r] * nm0[r]);
        }
    }
}

// ---------------- final gather (F=64, identity, fp16 y) ----------------
__global__ __launch_bounds__(256) void gather_fin64(
    const _Float16* __restrict__ y, const int* __restrict__ row_ptr,
    const int* __restrict__ sorted_src, const float* __restrict__ norm,
    const float* __restrict__ bias, float* __restrict__ out) {
    const int wave = threadIdx.x >> 6;
    const int lane = threadIdx.x & 63;
    const int g = lane >> 4, j = lane & 15;
    const int n = blockIdx.x * 16 + wave * 4 + g;
    const int beg = row_ptr[n];
    const int deg = row_ptr[n + 1] - beg;
    int dmax = deg;
    dmax = max(dmax, __shfl_xor(dmax, 16));
    dmax = max(dmax, __shfl_xor(dmax, 32));

    f32x4 acc = (f32x4){0.f, 0.f, 0.f, 0.f};
    for (int i = 0; i < dmax; i += 8) {
        int sarr[8];
#pragma unroll
        for (int u = 0; u < 8; ++u)
            sarr[u] = (i + u < deg) ? sorted_src[beg + i + u] : -1;
        half4 h[8];
#pragma unroll
        for (int u = 0; u < 8; ++u)
            if (sarr[u] >= 0)
                h[u] = *(const half4*)(y + ((size_t)sarr[u] << 6) + j * 4);
#pragma unroll
        for (int u = 0; u < 8; ++u)
            if (sarr[u] >= 0) acc += __builtin_convertvector(h[u], f32x4);
    }

    const half4 sh = *(const half4*)(y + ((size_t)n << 6) + j * 4);
    const f32x4 b = *(const f32x4*)(bias + j * 4);
    const float nm = norm[n];
    f32x4 o;
    o[0] = (acc[0] + (float)sh[0]) * nm + b[0];
    o[1] = (acc[1] + (float)sh[1]) * nm + b[1];
    o[2] = (acc[2] + (float)sh[2]) * nm + b[2];
    o[3] = (acc[3] + (float)sh[3]) * nm + b[3];
    __builtin_nontemporal_store(o, (f32x4*)(out + ((size_t)n << 6) + j * 4));
}

extern "C" void kernel_launch(void* const* d_in, const int* in_sizes, int n_in,
                              void* d_out, int out_size, void* d_ws, size_t ws_size,
                              hipStream_t stream) {
    const float* inputs = (const float*)d_in[0];
    const int* edges = (const int*)d_in[1];
    const int* src = edges;
    const int* dst = edges + NEDGES;
    const float* w_in  = (const float*)d_in[2];
    const float* b_in  = (const float*)d_in[3];
    const float* w1    = (const float*)d_in[4];
    const float* b1    = (const float*)d_in[5];
    const float* w2    = (const float*)d_in[6];
    const float* b2    = (const float*)d_in[7];
    const float* w_out = (const float*)d_in[8];
    const float* b_out = (const float*)d_in[9];

    float* out  = (float*)d_out;
    float* xout = out;                                // [N, 64]
    float* x    = out + (size_t)NNODES * OUTDIM;      // [N, 128] fp32 x (final only)

    char* p = (char*)d_ws;
    auto alloc = [&](size_t bytes) {
        char* r = p;
        p += (bytes + 63) & ~(size_t)63;
        return r;
    };
    int* deg        = (int*)alloc(NNODES * 4);
    int* epos       = (int*)alloc(NEDGES * 4);
    int* row_ptr    = (int*)alloc((NNODES + 1) * 4);
    int* bsum       = (int*)alloc(256 * 4);
    int* bofs       = (int*)alloc(256 * 4);
    int* sorted_src = (int*)alloc(NEDGES * 4);
    float* normb    = (float*)alloc(NNODES * 4);
    unsigned short* wT = (unsigned short*)alloc((size_t)245760 * 2);  // 7*32768+16384
    _Float16* w2f   = (_Float16*)alloc((size_t)6 * 16384 * 2);
    unsigned short* xc_x = (unsigned short*)alloc((size_t)NPAD * 256 * 2);
    unsigned short* xc_in = (unsigned short*)alloc((size_t)NPAD * 256 * 2);
    _Float16* Ya    = (_Float16*)alloc((size_t)NPAD * 128 * 2);
    _Float16* Yb    = (_Float16*)alloc((size_t)NPAD * 128 * 2);

    // ---- CSR + norm + weight prep ----
    hipMemsetAsync(deg, 0, NNODES * sizeof(int), stream);
    count_kernel<<<(NEDGES + 255) / 256, 256, 0, stream>>>(dst, deg, epos);
    bsum_kernel<<<196, 256, 0, stream>>>(deg, bsum);
    bscan_kernel<<<1, 256, 0, stream>>>(bsum, bofs);
    emit_kernel<<<196, 256, 0, stream>>>(deg, bofs, row_ptr, normb);
    fill_kernel<<<(NEDGES + 255) / 256, 256, 0, stream>>>(src, dst, epos, row_ptr, sorted_src);
    prep_w_kernel<<<864, 256, 0, stream>>>(w_in, w1, w2, w_out, wT, w2f);

    // input layer: x @ w_in -> Ya; then fused {gather+b_in -> xc_x} + {w1_0 GEMM} -> Yb
    split_x_kernel<<<(NPAD * 64) / 256, 256, 0, stream>>>(inputs, xc_in);
    gemm_bf_kernel<128><<<GEMM_GRID, GEMM_BLK, 0, stream>>>(xc_in, wT, normb, Ya);
    fgb_kernel<0, 128, false, true><<<GEMM_GRID, GEMM_BLK, 0, stream>>>(
        Ya, row_ptr, sorted_src, normb, b_in, nullptr,
        wT + (size_t)1 * 32768, xc_x, nullptr, Yb);

    // 6 residual blocks
    for (int i = 0; i < 6; ++i) {
        fgg_f16_kernel<<<GEMM_GRID, GEMM_BLK, 0, stream>>>(
            Yb, row_ptr, sorted_src, normb, b1 + i * HDIM,
            w2f + (size_t)i * 16384, Ya);
        if (i < 5)
            fgb_kernel<1, 128, false, true><<<GEMM_GRID, GEMM_BLK, 0, stream>>>(
                Ya, row_ptr, sorted_src, normb, b2 + i * HDIM, xc_x,
                wT + (size_t)(2 + i) * 32768, xc_x, nullptr, Yb);
        else
            fgb_kernel<1, 64, true, false><<<GEMM_GRID, GEMM_BLK, 0, stream>>>(
                Ya, row_ptr, sorted_src, normb, b2 + i * HDIM, xc_x,
                wT + (size_t)7 * 32768, nullptr, x, Yb);
    }

    // final aggregation (identity conv epilogue)
    gather_fin64<<<NNODES / 16, 256, 0, stream>>>(
        Yb, row_ptr, sorted_src, normb, b_out, xout);
}

// Round 8
// 746.090 us; speedup vs baseline: 1.1272x; 1.1272x over previous
//
#include <hip/hip_runtime.h>

#define NNODES 50000
#define NPAD   50048   // 391 * 128
#define NEDGES 800000
#define HDIM 128
#define OUTDIM 64

#define GEMM_GRID 391
#define GEMM_BLK  512

typedef short short8 __attribute__((ext_vector_type(8)));
typedef _Float16 half8 __attribute__((ext_vector_type(8)));
typedef _Float16 half4 __attribute__((ext_vector_type(4)));
typedef float f32x4 __attribute__((ext_vector_type(4)));
typedef float f32x8 __attribute__((ext_vector_type(8)));

__device__ __forceinline__ unsigned short f2bf(float f) {
    unsigned int u = __builtin_bit_cast(unsigned int, f);
    unsigned int r = (u + 0x7FFFu + ((u >> 16) & 1u)) >> 16;
    return (unsigned short)r;
}
__device__ __forceinline__ float bf2f(unsigned short b) {
    unsigned int u = ((unsigned int)b) << 16;
    return __builtin_bit_cast(float, u);
}

// ---------------- CSR build ----------------
__global__ void count_kernel(const int* __restrict__ dst, int* __restrict__ deg,
                             int* __restrict__ epos) {
    int e = blockIdx.x * 256 + threadIdx.x;
    if (e < NEDGES) epos[e] = atomicAdd(&deg[dst[e]], 1);
}

__global__ __launch_bounds__(256) void bsum_kernel(const int* __restrict__ deg,
                                                   int* __restrict__ bsum) {
    __shared__ int red[256];
    int i = blockIdx.x * 256 + threadIdx.x;
    red[threadIdx.x] = (i < NNODES) ? deg[i] : 0;
    __syncthreads();
    for (int off = 128; off; off >>= 1) {
        if (threadIdx.x < off) red[threadIdx.x] += red[threadIdx.x + off];
        __syncthreads();
    }
    if (threadIdx.x == 0) bsum[blockIdx.x] = red[0];
}

__global__ __launch_bounds__(256) void bscan_kernel(const int* __restrict__ bsum,
                                                    int* __restrict__ bofs) {
    __shared__ int s[256];
    int t = threadIdx.x;
    int v = (t < 196) ? bsum[t] : 0;
    s[t] = v;
    __syncthreads();
    for (int off = 1; off < 256; off <<= 1) {
        int u = (t >= off) ? s[t - off] : 0;
        __syncthreads();
        s[t] += u;
        __syncthreads();
    }
    if (t < 196) bofs[t] = s[t] - v;  // exclusive
}

__global__ __launch_bounds__(256) void emit_kernel(
    const int* __restrict__ deg, const int* __restrict__ bofs,
    int* __restrict__ row_ptr, float* __restrict__ norm) {
    __shared__ int s[256];
    int t = threadIdx.x;
    int i = blockIdx.x * 256 + t;
    int v = (i < NNODES) ? deg[i] : 0;
    s[t] = v;
    __syncthreads();
    for (int off = 1; off < 256; off <<= 1) {
        int u = (t >= off) ? s[t - off] : 0;
        __syncthreads();
        s[t] += u;
        __syncthreads();
    }
    int excl = s[t] - v + bofs[blockIdx.x];
    if (i < NNODES) {
        row_ptr[i] = excl;
        norm[i] = rsqrtf(1.0f + (float)v);
    }
    if (i == NNODES - 1) row_ptr[NNODES] = NEDGES;
}

__global__ void fill_kernel(const int* __restrict__ src, const int* __restrict__ dst,
                            const int* __restrict__ epos, const int* __restrict__ row_ptr,
                            int* __restrict__ sorted_src) {
    int e = blockIdx.x * 256 + threadIdx.x;
    if (e < NEDGES) sorted_src[row_ptr[dst[e]] + epos[e]] = src[e];
}

// -------- window-16 degree rank-sort (wave load balance, locality-safe) -----
// Within each aligned 16-node window, rank nodes by degree (desc); the 4
// nodes sharing a wave-quad then have near-equal degree. A node moves at
// most 15 slots -> y/xc access locality is preserved (unlike a global sort).
// Pad region sorts to identity (deg=-1, rank by index).
__global__ __launch_bounds__(256) void dsort16_kernel(
    const int* __restrict__ deg, int* __restrict__ perm) {
    __shared__ int dl[256];
    int t = threadIdx.x;
    int i = blockIdx.x * 256 + t;
    int d = (i < NNODES) ? deg[i] : -1;
    dl[t] = d;
    __syncthreads();
    if (i < NPAD) {
        int wbase = t & ~15;
        int s = t & 15;
        int rank = 0;
#pragma unroll
        for (int k = 0; k < 16; ++k) {
            int dk = dl[wbase + k];
            rank += (dk > d) || (dk == d && k < s);
        }
        perm[blockIdx.x * 256 + wbase + rank] = i;
    }
}

// ---------------- weight prep ----------------
// bf16 hi/lo (wT): w_in slot 0, w1[m] slot 1+m, w_out slot 7 (64 rows).
// f16 single (w2f): w2[m] at m*16384, layout [n][128].
__global__ __launch_bounds__(256) void prep_w_kernel(
    const float* __restrict__ w_in, const float* __restrict__ w1,
    const float* __restrict__ w2, const float* __restrict__ w_out,
    unsigned short* __restrict__ wT, _Float16* __restrict__ w2f) {
    int idx = blockIdx.x * 256 + threadIdx.x;  // total 221184 = 864*256
    if (idx < 16384 + 98304) {
        const float* W;
        unsigned short* o;
        int e;
        if (idx < 16384) {
            W = w_in; o = wT; e = idx;
        } else {
            int j = idx - 16384; int m = j >> 14; e = j & 16383;
            W = w1 + ((size_t)m << 14); o = wT + (size_t)(1 + m) * 32768;
        }
        int k = e >> 7, n = e & 127;
        float v = W[e];
        unsigned short h = f2bf(v);
        o[(size_t)n * 256 + k] = h;
        o[(size_t)n * 256 + 128 + k] = f2bf(v - bf2f(h));
    } else if (idx < 16384 + 196608) {
        int j = idx - 16384 - 98304; int m = j >> 14; int e = j & 16383;
        int k = e >> 7, n = e & 127;
        w2f[(size_t)m * 16384 + n * 128 + k] = (_Float16)w2[((size_t)m << 14) + e];
    } else {
        int e = idx - 212992;  // w_out: 8192 elements
        int k = e >> 6, n = e & 63;
        float v = w_out[e];
        unsigned short h = f2bf(v);
        unsigned short* o = wT + (size_t)7 * 32768;
        o[(size_t)n * 256 + k] = h;
        o[(size_t)n * 256 + 128 + k] = f2bf(v - bf2f(h));
    }
}

// ---------------- x split (input layer only) ----------------
__global__ __launch_bounds__(256) void split_x_kernel(
    const float* __restrict__ x, unsigned short* __restrict__ xc) {
    int gid = blockIdx.x * 256 + threadIdx.x;
    int row = gid >> 6;
    int kk = (gid & 63) * 2;
    float2 v = {0.f, 0.f};
    if (row < NNODES) v = *(const float2*)(x + (size_t)row * 128 + kk);
    unsigned short h0 = f2bf(v.x), h1 = f2bf(v.y);
    unsigned short l0 = f2bf(v.x - bf2f(h0)), l1 = f2bf(v.y - bf2f(h1));
    *(unsigned int*)(xc + (size_t)row * 256 + kk) =
        (unsigned int)h0 | ((unsigned int)h1 << 16);
    *(unsigned int*)(xc + (size_t)row * 256 + 128 + kk) =
        (unsigned int)l0 | ((unsigned int)l1 << 16);
}

// ---------------- bf16 hi/lo streaming MFMA GEMM ----------------
template <int NCOLS>
__global__ __launch_bounds__(GEMM_BLK) void gemm_bf_kernel(
    const unsigned short* __restrict__ xc, const unsigned short* __restrict__ wT,
    const float* __restrict__ norm, _Float16* __restrict__ y) {
    __shared__ unsigned short Blds[NCOLS * 256];
    const int t = threadIdx.x;
    const int wave = t >> 6, lane = t & 63, quad = lane >> 4, l16 = lane & 15;

    constexpr int NCH = NCOLS * 32;  // 16B chunks total
#pragma unroll
    for (int i = 0; i < NCH / GEMM_BLK; ++i) {
        int C = i * GEMM_BLK + t;
        int n = C >> 5, c = C & 31;
        const unsigned short* gp = wT + ((size_t)n << 8) + ((c ^ (n & 7)) << 3);
        unsigned short* lp = Blds + ((size_t)C << 3);
        __builtin_amdgcn_global_load_lds(
            (const __attribute__((address_space(1))) void*)gp,
            (__attribute__((address_space(3))) void*)lp, 16, 0, 0);
    }
    __syncthreads();

    const int wid = blockIdx.x * (GEMM_BLK / 64) + wave;
    const int sw = l16 & 7;
    const int rb0 = wid * 16;

    short8 a0[8];
    const unsigned short* ap0 = xc + ((size_t)(rb0 + l16) << 8) + quad * 8;
#pragma unroll
    for (int ck = 0; ck < 8; ++ck) a0[ck] = *(const short8*)(ap0 + ck * 32);

    float nm0[4];
#pragma unroll
    for (int r = 0; r < 4; ++r) {
        int r0 = rb0 + quad * 4 + r;
        nm0[r] = norm[r0 < NNODES ? r0 : 0];
    }

#pragma unroll
    for (int nt = 0; nt < NCOLS / 16; ++nt) {
        const unsigned short* bp = Blds + ((size_t)(nt * 16 + l16) << 8);
        short8 bh[4], bl[4];
#pragma unroll
        for (int ck = 0; ck < 4; ++ck) {
            bh[ck] = *(const short8*)(bp + (((ck * 4 + quad) ^ sw) << 3));
            bl[ck] = *(const short8*)(bp + (((16 + ck * 4 + quad) ^ sw) << 3));
        }
        f32x4 ac0 = (f32x4){0.f, 0.f, 0.f, 0.f};
#pragma unroll
        for (int ck = 0; ck < 4; ++ck) {
            ac0 = __builtin_amdgcn_mfma_f32_16x16x32_bf16(a0[ck], bh[ck], ac0, 0, 0, 0);
            ac0 = __builtin_amdgcn_mfma_f32_16x16x32_bf16(a0[ck], bl[ck], ac0, 0, 0, 0);
            ac0 = __builtin_amdgcn_mfma_f32_16x16x32_bf16(a0[4 + ck], bh[ck], ac0, 0, 0, 0);
        }
        int col = nt * 16 + l16;
#pragma unroll
        for (int r = 0; r < 4; ++r) {
            int r0 = rb0 + quad * 4 + r;
            if (r0 < NNODES) y[(size_t)r0 * NCOLS + col] = (_Float16)(ac0[r] * nm0[r]);
        }
    }
}

// -------- FUSED gather+finalize+f16 GEMM (fgg) ------------------------------
// Wave gathers & finalizes its 16 nodes (window-sorted via perm), writes them
// to wave-private LDS, then runs the f16 MFMA; output rows routed through
// the same perm. 64KB LDS total -> 2 blocks/CU (16 waves) in gather phase.
__global__ __launch_bounds__(GEMM_BLK) void fgg_f16_kernel(
    const _Float16* __restrict__ y, const int* __restrict__ row_ptr,
    const int* __restrict__ sorted_src, const float* __restrict__ norm,
    const float* __restrict__ bias, const _Float16* __restrict__ wf,
    _Float16* __restrict__ yout, const int* __restrict__ perm) {
    __shared__ _Float16 Blds[128 * 128];          // 32 KB
    __shared__ _Float16 Alds[8 * 16 * 128];       // 32 KB, 4KB per wave
    const int t = threadIdx.x;
    const int wave = t >> 6, lane = t & 63, quad = lane >> 4, l16 = lane & 15;

    // ---- B stage, then immediate barrier ----
#pragma unroll
    for (int i = 0; i < 2048 / GEMM_BLK; ++i) {
        int C = i * GEMM_BLK + t;
        int n = C >> 4, c = C & 15;
        const _Float16* gp = wf + ((size_t)n << 7) + ((c ^ (n & 7)) << 3);
        _Float16* lp = Blds + ((size_t)C << 3);
        __builtin_amdgcn_global_load_lds(
            (const __attribute__((address_space(1))) void*)gp,
            (__attribute__((address_space(3))) void*)lp, 16, 0, 0);
    }
    __syncthreads();

    const int wid = blockIdx.x * (GEMM_BLK / 64) + wave;
    const int rb0 = wid * 16;
    _Float16* Aw = Alds + (size_t)wave * 2048;
    const int g = quad, j = l16;

    // ---- gather phase: 4 batches x 4 nodes/wave, 16 lanes per node ----
    for (int tb = 0; tb < 4; ++tb) {
        const int n = perm[rb0 + tb * 4 + g];
        const bool valid = n < NNODES;
        const int beg = valid ? row_ptr[n] : 0;
        const int dg = valid ? (row_ptr[n + 1] - beg) : 0;
        int dmax = dg;
        dmax = max(dmax, __shfl_xor(dmax, 16));
        dmax = max(dmax, __shfl_xor(dmax, 32));

        f32x8 acc = (f32x8){0.f, 0.f, 0.f, 0.f, 0.f, 0.f, 0.f, 0.f};
        for (int i = 0; i < dmax; i += 8) {
            int sarr[8];
#pragma unroll
            for (int u = 0; u < 8; ++u)
                sarr[u] = (i + u < dg) ? sorted_src[beg + i + u] : -1;
            half8 h[8];
#pragma unroll
            for (int u = 0; u < 8; ++u)
                if (sarr[u] >= 0)
                    h[u] = *(const half8*)(y + ((size_t)sarr[u] << 7) + j * 8);
#pragma unroll
            for (int u = 0; u < 8; ++u)
                if (sarr[u] >= 0) acc += __builtin_convertvector(h[u], f32x8);
        }

        half8 o;
        if (valid) {
            const half8 sh = *(const half8*)(y + ((size_t)n << 7) + j * 8);
            const f32x4 b0 = *(const f32x4*)(bias + j * 8);
            const f32x4 b1 = *(const f32x4*)(bias + j * 8 + 4);
            const float bb[8] = {b0[0], b0[1], b0[2], b0[3], b1[0], b1[1], b1[2], b1[3]};
            const float nm = norm[n];
#pragma unroll
            for (int c = 0; c < 8; ++c) {
                float v = (acc[c] + (float)sh[c]) * nm + bb[c];
                v = v >= 0.f ? v : 0.01f * v;
                o[c] = (_Float16)v;
            }
        } else {
#pragma unroll
            for (int c = 0; c < 8; ++c) o[c] = (_Float16)0.f;
        }
        *(half8*)(Aw + (size_t)(tb * 4 + g) * 128 + j * 8) = o;
    }

    // ---- MFMA phase (A wave-local, B valid since barrier) ----
    const int sw = l16 & 7;
    half8 a0[4];
#pragma unroll
    for (int ck = 0; ck < 4; ++ck)
        a0[ck] = *(const half8*)(Aw + (size_t)l16 * 128 + ck * 32 + quad * 8);

    int pr[4];
    float nm0[4];
#pragma unroll
    for (int r = 0; r < 4; ++r) {
        int p = perm[rb0 + quad * 4 + r];
        pr[r] = p;
        nm0[r] = norm[p < NNODES ? p : 0];
    }

#pragma unroll
    for (int nt = 0; nt < 8; ++nt) {
        const _Float16* bp = Blds + ((size_t)(nt * 16 + l16) << 7);
        half8 b[4];
#pragma unroll
        for (int ck = 0; ck < 4; ++ck)
            b[ck] = *(const half8*)(bp + (((ck * 4 + quad) ^ sw) << 3));
        f32x4 ac0 = (f32x4){0.f, 0.f, 0.f, 0.f};
#pragma unroll
        for (int ck = 0; ck < 4; ++ck)
            ac0 = __builtin_amdgcn_mfma_f32_16x16x32_f16(a0[ck], b[ck], ac0, 0, 0, 0);
        int col = nt * 16 + l16;
#pragma unroll
        for (int r = 0; r < 4; ++r) {
            if (pr[r] < NNODES)
                yout[(size_t)pr[r] * 128 + col] = (_Float16)(ac0[r] * nm0[r]);
        }
    }
}

// ---------------- fused gather + finalize (F=128, fp16 y) ----------------
// Nodes assigned via window-16 degree-sorted perm (wave balance, local).
template <int MODE, bool WOUT, bool OUT16>
__global__ __launch_bounds__(256) void gather_fin128(
    const _Float16* __restrict__ y, const int* __restrict__ row_ptr,
    const int* __restrict__ sorted_src, const float* __restrict__ norm,
    const float* __restrict__ bias, const unsigned short* __restrict__ xcres,
    float* __restrict__ out, unsigned short* __restrict__ xcout,
    _Float16* __restrict__ h16, const int* __restrict__ perm) {
    const int wave = threadIdx.x >> 6;
    const int lane = threadIdx.x & 63;
    const int g = lane >> 4, j = lane & 15;
    const int n = perm[blockIdx.x * 16 + wave * 4 + g];
    const int beg = row_ptr[n];
    const int deg = row_ptr[n + 1] - beg;
    int dmax = deg;
    dmax = max(dmax, __shfl_xor(dmax, 16));
    dmax = max(dmax, __shfl_xor(dmax, 32));

    f32x8 acc = (f32x8){0.f, 0.f, 0.f, 0.f, 0.f, 0.f, 0.f, 0.f};

    for (int i = 0; i < dmax; i += 8) {
        int sarr[8];
#pragma unroll
        for (int u = 0; u < 8; ++u)
            sarr[u] = (i + u < deg) ? sorted_src[beg + i + u] : -1;
        half8 h[8];
#pragma unroll
        for (int u = 0; u < 8; ++u)
            if (sarr[u] >= 0)
                h[u] = *(const half8*)(y + ((size_t)sarr[u] << 7) + j * 8);
#pragma unroll
        for (int u = 0; u < 8; ++u)
            if (sarr[u] >= 0) acc += __builtin_convertvector(h[u], f32x8);
    }

    const half8 sh = *(const half8*)(y + ((size_t)n << 7) + j * 8);
    const f32x4 b0 = *(const f32x4*)(bias + j * 8);
    const f32x4 b1 = *(const f32x4*)(bias + j * 8 + 4);
    const float bb[8] = {b0[0], b0[1], b0[2], b0[3], b1[0], b1[1], b1[2], b1[3]};
    const float nm = norm[n];
    float v[8];
#pragma unroll
    for (int c = 0; c < 8; ++c) {
        float t = (acc[c] + (float)sh[c]) * nm + bb[c];
        v[c] = t >= 0.f ? t : 0.01f * t;
    }
    if (MODE == 1) {
        short8 hw = __builtin_nontemporal_load(
            (const short8*)(xcres + ((size_t)n << 8) + j * 8));
        short8 lw = __builtin_nontemporal_load(
            (const short8*)(xcres + ((size_t)n << 8) + 128 + j * 8));
#pragma unroll
        for (int c = 0; c < 8; ++c) {
            float xr = bf2f((unsigned short)hw[c]) + bf2f((unsigned short)lw[c]);
            v[c] = (xr + v[c]) * 0.5f;
        }
    }
    if (WOUT) {
        f32x4 o0 = (f32x4){v[0], v[1], v[2], v[3]};
        f32x4 o1 = (f32x4){v[4], v[5], v[6], v[7]};
        __builtin_nontemporal_store(o0, (f32x4*)(out + ((size_t)n << 7) + j * 8));
        __builtin_nontemporal_store(o1, (f32x4*)(out + ((size_t)n << 7) + j * 8 + 4));
    }
    if (OUT16) {
        half8 o;
#pragma unroll
        for (int c = 0; c < 8; ++c) o[c] = (_Float16)v[c];
        *(half8*)(h16 + ((size_t)n << 7) + j * 8) = o;
    } else {
        short8 hi, lo;
#pragma unroll
        for (int c = 0; c < 8; ++c) {
            unsigned short hv = f2bf(v[c]);
            hi[c] = (short)hv;
            lo[c] = (short)f2bf(v[c] - bf2f(hv));
        }
        *(short8*)(xcout + ((size_t)n << 8) + j * 8) = hi;
        *(short8*)(xcout + ((size_t)n << 8) + 128 + j * 8) = lo;
    }
}

// ---------------- final gather (F=64, identity, fp16 y) ----------------
__global__ __launch_bounds__(256) void gather_fin64(
    const _Float16* __restrict__ y, const int* __restrict__ row_ptr,
    const int* __restrict__ sorted_src, const float* __restrict__ norm,
    const float* __restrict__ bias, float* __restrict__ out,
    const int* __restrict__ perm) {
    const int wave = threadIdx.x >> 6;
    const int lane = threadIdx.x & 63;
    const int g = lane >> 4, j = lane & 15;
    const int n = perm[blockIdx.x * 16 + wave * 4 + g];
    const int beg = row_ptr[n];
    const int deg = row_ptr[n + 1] - beg;
    int dmax = deg;
    dmax = max(dmax, __shfl_xor(dmax, 16));
    dmax = max(dmax, __shfl_xor(dmax, 32));

    f32x4 acc = (f32x4){0.f, 0.f, 0.f, 0.f};
    for (int i = 0; i < dmax; i += 8) {
        int sarr[8];
#pragma unroll
        for (int u = 0; u < 8; ++u)
            sarr[u] = (i + u < deg) ? sorted_src[beg + i + u] : -1;
        half4 h[8];
#pragma unroll
        for (int u = 0; u < 8; ++u)
            if (sarr[u] >= 0)
                h[u] = *(const half4*)(y + ((size_t)sarr[u] << 6) + j * 4);
#pragma unroll
        for (int u = 0; u < 8; ++u)
            if (sarr[u] >= 0) acc += __builtin_convertvector(h[u], f32x4);
    }

    const half4 sh = *(const half4*)(y + ((size_t)n << 6) + j * 4);
    const f32x4 b = *(const f32x4*)(bias + j * 4);
    const float nm = norm[n];
    f32x4 o;
    o[0] = (acc[0] + (float)sh[0]) * nm + b[0];
    o[1] = (acc[1] + (float)sh[1]) * nm + b[1];
    o[2] = (acc[2] + (float)sh[2]) * nm + b[2];
    o[3] = (acc[3] + (float)sh[3]) * nm + b[3];
    __builtin_nontemporal_store(o, (f32x4*)(out + ((size_t)n << 6) + j * 4));
}

extern "C" void kernel_launch(void* const* d_in, const int* in_sizes, int n_in,
                              void* d_out, int out_size, void* d_ws, size_t ws_size,
                              hipStream_t stream) {
    const float* inputs = (const float*)d_in[0];
    const int* edges = (const int*)d_in[1];
    const int* src = edges;
    const int* dst = edges + NEDGES;
    const float* w_in  = (const float*)d_in[2];
    const float* b_in  = (const float*)d_in[3];
    const float* w1    = (const float*)d_in[4];
    const float* b1    = (const float*)d_in[5];
    const float* w2    = (const float*)d_in[6];
    const float* b2    = (const float*)d_in[7];
    const float* w_out = (const float*)d_in[8];
    const float* b_out = (const float*)d_in[9];

    float* out  = (float*)d_out;
    float* xout = out;                                // [N, 64]
    float* x    = out + (size_t)NNODES * OUTDIM;      // [N, 128] fp32 x (final only)

    char* p = (char*)d_ws;
    auto alloc = [&](size_t bytes) {
        char* r = p;
        p += (bytes + 63) & ~(size_t)63;
        return r;
    };
    int* deg        = (int*)alloc(NNODES * 4);
    int* epos       = (int*)alloc(NEDGES * 4);
    int* row_ptr    = (int*)alloc((NNODES + 1) * 4);
    int* bsum       = (int*)alloc(256 * 4);
    int* bofs       = (int*)alloc(256 * 4);
    int* sorted_src = (int*)alloc(NEDGES * 4);
    float* normb    = (float*)alloc(NNODES * 4);
    int* perm       = (int*)alloc(NPAD * 4);
    unsigned short* wT = (unsigned short*)alloc((size_t)245760 * 2);  // 7*32768+16384
    _Float16* w2f   = (_Float16*)alloc((size_t)6 * 16384 * 2);
    unsigned short* xc_x = (unsigned short*)alloc((size_t)NPAD * 256 * 2);
    unsigned short* xc_in = (unsigned short*)alloc((size_t)NPAD * 256 * 2);
    _Float16* y2    = (_Float16*)alloc((size_t)NPAD * 128 * 2);
    _Float16* y     = (_Float16*)alloc((size_t)NNODES * HDIM * 2);

    // ---- CSR + norm + perm + weight prep ----
    hipMemsetAsync(deg, 0, NNODES * sizeof(int), stream);
    count_kernel<<<(NEDGES + 255) / 256, 256, 0, stream>>>(dst, deg, epos);
    dsort16_kernel<<<196, 256, 0, stream>>>(deg, perm);
    bsum_kernel<<<196, 256, 0, stream>>>(deg, bsum);
    bscan_kernel<<<1, 256, 0, stream>>>(bsum, bofs);
    emit_kernel<<<196, 256, 0, stream>>>(deg, bofs, row_ptr, normb);
    fill_kernel<<<(NEDGES + 255) / 256, 256, 0, stream>>>(src, dst, epos, row_ptr, sorted_src);
    prep_w_kernel<<<864, 256, 0, stream>>>(w_in, w1, w2, w_out, wT, w2f);

    // input layer
    split_x_kernel<<<(NPAD * 64) / 256, 256, 0, stream>>>(inputs, xc_in);
    gemm_bf_kernel<128><<<GEMM_GRID, GEMM_BLK, 0, stream>>>(xc_in, wT, normb, y);
    gather_fin128<0, false, false><<<NNODES / 16, 256, 0, stream>>>(
        y, row_ptr, sorted_src, normb, b_in, nullptr, nullptr, xc_x, nullptr, perm);

    // 6 residual blocks
    for (int i = 0; i < 6; ++i) {
        gemm_bf_kernel<128><<<GEMM_GRID, GEMM_BLK, 0, stream>>>(
            xc_x, wT + (size_t)(1 + i) * 32768, normb, y);
        fgg_f16_kernel<<<GEMM_GRID, GEMM_BLK, 0, stream>>>(
            y, row_ptr, sorted_src, normb, b1 + i * HDIM,
            w2f + (size_t)i * 16384, y2, perm);
        if (i < 5)
            gather_fin128<1, false, false><<<NNODES / 16, 256, 0, stream>>>(
                y2, row_ptr, sorted_src, normb, b2 + i * HDIM, xc_x, nullptr, xc_x, nullptr, perm);
        else
            gather_fin128<1, true, false><<<NNODES / 16, 256, 0, stream>>>(
                y2, row_ptr, sorted_src, normb, b2 + i * HDIM, xc_x, x, xc_x, nullptr, perm);
    }

    // output layer (H -> 64, identity)
    gemm_bf_kernel<64><<<GEMM_GRID, GEMM_BLK, 0, stream>>>(
        xc_x, wT + (size_t)7 * 32768, normb, y);
    gather_fin64<<<NNODES / 16, 256, 0, stream>>>(
        y, row_ptr, sorted_src, normb, b_out, xout, perm);
}

// Round 9
// 706.631 us; speedup vs baseline: 1.1901x; 1.0558x over previous
//
#include <hip/hip_runtime.h>

#define NNODES 50000
#define NPAD   50048   // 391 * 128
#define NEDGES 800000
#define HDIM 128
#define OUTDIM 64

#define GEMM_GRID 391
#define GEMM_BLK  512

typedef short short8 __attribute__((ext_vector_type(8)));
typedef _Float16 half8 __attribute__((ext_vector_type(8)));
typedef _Float16 half4 __attribute__((ext_vector_type(4)));
typedef float f32x4 __attribute__((ext_vector_type(4)));
typedef float f32x8 __attribute__((ext_vector_type(8)));

__device__ __forceinline__ unsigned short f2bf(float f) {
    unsigned int u = __builtin_bit_cast(unsigned int, f);
    unsigned int r = (u + 0x7FFFu + ((u >> 16) & 1u)) >> 16;
    return (unsigned short)r;
}
__device__ __forceinline__ float bf2f(unsigned short b) {
    unsigned int u = ((unsigned int)b) << 16;
    return __builtin_bit_cast(float, u);
}

// ---------------- CSR build ----------------
__global__ void count_kernel(const int* __restrict__ dst, int* __restrict__ deg,
                             int* __restrict__ epos) {
    int e = blockIdx.x * 256 + threadIdx.x;
    if (e < NEDGES) epos[e] = atomicAdd(&deg[dst[e]], 1);
}

__global__ __launch_bounds__(256) void bsum_kernel(const int* __restrict__ deg,
                                                   int* __restrict__ bsum) {
    __shared__ int red[256];
    int i = blockIdx.x * 256 + threadIdx.x;
    red[threadIdx.x] = (i < NNODES) ? deg[i] : 0;
    __syncthreads();
    for (int off = 128; off; off >>= 1) {
        if (threadIdx.x < off) red[threadIdx.x] += red[threadIdx.x + off];
        __syncthreads();
    }
    if (threadIdx.x == 0) bsum[blockIdx.x] = red[0];
}

__global__ __launch_bounds__(256) void bscan_kernel(const int* __restrict__ bsum,
                                                    int* __restrict__ bofs) {
    __shared__ int s[256];
    int t = threadIdx.x;
    int v = (t < 196) ? bsum[t] : 0;
    s[t] = v;
    __syncthreads();
    for (int off = 1; off < 256; off <<= 1) {
        int u = (t >= off) ? s[t - off] : 0;
        __syncthreads();
        s[t] += u;
        __syncthreads();
    }
    if (t < 196) bofs[t] = s[t] - v;  // exclusive
}

__global__ __launch_bounds__(256) void emit_kernel(
    const int* __restrict__ deg, const int* __restrict__ bofs,
    int* __restrict__ row_ptr, float* __restrict__ norm) {
    __shared__ int s[256];
    int t = threadIdx.x;
    int i = blockIdx.x * 256 + t;
    int v = (i < NNODES) ? deg[i] : 0;
    s[t] = v;
    __syncthreads();
    for (int off = 1; off < 256; off <<= 1) {
        int u = (t >= off) ? s[t - off] : 0;
        __syncthreads();
        s[t] += u;
        __syncthreads();
    }
    int excl = s[t] - v + bofs[blockIdx.x];
    if (i < NNODES) {
        row_ptr[i] = excl;
        norm[i] = rsqrtf(1.0f + (float)v);
    }
    if (i == NNODES - 1) row_ptr[NNODES] = NEDGES;
}

__global__ void fill_kernel(const int* __restrict__ src, const int* __restrict__ dst,
                            const int* __restrict__ epos, const int* __restrict__ row_ptr,
                            int* __restrict__ sorted_src) {
    int e = blockIdx.x * 256 + threadIdx.x;
    if (e < NEDGES) sorted_src[row_ptr[dst[e]] + epos[e]] = src[e];
}

// ---------------- weight prep ----------------
// wT: w_in bf16 hi/lo (input GEMM keeps full precision).
// w1f/w2f: per-block f16, layout [n][128] (k-major rows).
// woutf: w_out f16, [n=64][k=128].
__global__ __launch_bounds__(256) void prep_w_kernel(
    const float* __restrict__ w_in, const float* __restrict__ w1,
    const float* __restrict__ w2, const float* __restrict__ w_out,
    unsigned short* __restrict__ wT, _Float16* __restrict__ w1f,
    _Float16* __restrict__ w2f, _Float16* __restrict__ woutf) {
    int idx = blockIdx.x * 256 + threadIdx.x;  // total 221184 = 864*256
    if (idx < 16384) {
        int e = idx;
        int k = e >> 7, n = e & 127;
        float v = w_in[e];
        unsigned short h = f2bf(v);
        wT[(size_t)n * 256 + k] = h;
        wT[(size_t)n * 256 + 128 + k] = f2bf(v - bf2f(h));
    } else if (idx < 16384 + 98304) {
        int j = idx - 16384; int m = j >> 14; int e = j & 16383;
        int k = e >> 7, n = e & 127;
        w1f[(size_t)m * 16384 + n * 128 + k] = (_Float16)w1[((size_t)m << 14) + e];
    } else if (idx < 16384 + 196608) {
        int j = idx - 16384 - 98304; int m = j >> 14; int e = j & 16383;
        int k = e >> 7, n = e & 127;
        w2f[(size_t)m * 16384 + n * 128 + k] = (_Float16)w2[((size_t)m << 14) + e];
    } else {
        int e = idx - 212992;  // w_out: 8192 elements
        int k = e >> 6, n = e & 63;
        woutf[(size_t)n * 128 + k] = (_Float16)w_out[e];
    }
}

// ---------------- x split (input layer only) ----------------
__global__ __launch_bounds__(256) void split_x_kernel(
    const float* __restrict__ x, unsigned short* __restrict__ xc) {
    int gid = blockIdx.x * 256 + threadIdx.x;
    int row = gid >> 6;
    int kk = (gid & 63) * 2;
    float2 v = {0.f, 0.f};
    if (row < NNODES) v = *(const float2*)(x + (size_t)row * 128 + kk);
    unsigned short h0 = f2bf(v.x), h1 = f2bf(v.y);
    unsigned short l0 = f2bf(v.x - bf2f(h0)), l1 = f2bf(v.y - bf2f(h1));
    *(unsigned int*)(xc + (size_t)row * 256 + kk) =
        (unsigned int)h0 | ((unsigned int)h1 << 16);
    *(unsigned int*)(xc + (size_t)row * 256 + 128 + kk) =
        (unsigned int)l0 | ((unsigned int)l1 << 16);
}

// ---------------- bf16 hi/lo streaming MFMA GEMM (input layer only) --------
template <int NCOLS>
__global__ __launch_bounds__(GEMM_BLK) void gemm_bf_kernel(
    const unsigned short* __restrict__ xc, const unsigned short* __restrict__ wT,
    const float* __restrict__ norm, _Float16* __restrict__ y) {
    __shared__ unsigned short Blds[NCOLS * 256];
    const int t = threadIdx.x;
    const int wave = t >> 6, lane = t & 63, quad = lane >> 4, l16 = lane & 15;

    constexpr int NCH = NCOLS * 32;  // 16B chunks total
#pragma unroll
    for (int i = 0; i < NCH / GEMM_BLK; ++i) {
        int C = i * GEMM_BLK + t;
        int n = C >> 5, c = C & 31;
        const unsigned short* gp = wT + ((size_t)n << 8) + ((c ^ (n & 7)) << 3);
        unsigned short* lp = Blds + ((size_t)C << 3);
        __builtin_amdgcn_global_load_lds(
            (const __attribute__((address_space(1))) void*)gp,
            (__attribute__((address_space(3))) void*)lp, 16, 0, 0);
    }
    __syncthreads();

    const int wid = blockIdx.x * (GEMM_BLK / 64) + wave;
    const int sw = l16 & 7;
    const int rb0 = wid * 16;

    short8 a0[8];
    const unsigned short* ap0 = xc + ((size_t)(rb0 + l16) << 8) + quad * 8;
#pragma unroll
    for (int ck = 0; ck < 8; ++ck) a0[ck] = *(const short8*)(ap0 + ck * 32);

    float nm0[4];
#pragma unroll
    for (int r = 0; r < 4; ++r) {
        int r0 = rb0 + quad * 4 + r;
        nm0[r] = norm[r0 < NNODES ? r0 : 0];
    }

#pragma unroll
    for (int nt = 0; nt < NCOLS / 16; ++nt) {
        const unsigned short* bp = Blds + ((size_t)(nt * 16 + l16) << 8);
        short8 bh[4], bl[4];
#pragma unroll
        for (int ck = 0; ck < 4; ++ck) {
            bh[ck] = *(const short8*)(bp + (((ck * 4 + quad) ^ sw) << 3));
            bl[ck] = *(const short8*)(bp + (((16 + ck * 4 + quad) ^ sw) << 3));
        }
        f32x4 ac0 = (f32x4){0.f, 0.f, 0.f, 0.f};
#pragma unroll
        for (int ck = 0; ck < 4; ++ck) {
            ac0 = __builtin_amdgcn_mfma_f32_16x16x32_bf16(a0[ck], bh[ck], ac0, 0, 0, 0);
            ac0 = __builtin_amdgcn_mfma_f32_16x16x32_bf16(a0[ck], bl[ck], ac0, 0, 0, 0);
            ac0 = __builtin_amdgcn_mfma_f32_16x16x32_bf16(a0[4 + ck], bh[ck], ac0, 0, 0, 0);
        }
        int col = nt * 16 + l16;
#pragma unroll
        for (int r = 0; r < 4; ++r) {
            int r0 = rb0 + quad * 4 + r;
            if (r0 < NNODES) y[(size_t)r0 * NCOLS + col] = (_Float16)(ac0[r] * nm0[r]);
        }
    }
}

// -------- FUSED gather+finalize+f16 GEMM (fga) ------------------------------
// Wave gathers & finalizes its 16 nodes (leaky, optional residual from hi/lo
// xcres; optional hi/lo state write and fp32 x write), stores rows f16 into
// wave-private LDS, then runs the f16 MFMA against wf. 64KB LDS -> 2 blocks/CU
// (16 waves) in the gather phase; fast waves' MFMA overlaps slow gathers.
template <int MODE, int NCOLS, bool WRXC, bool WOUT>
__global__ __launch_bounds__(GEMM_BLK) void fga_kernel(
    const _Float16* __restrict__ y, const int* __restrict__ row_ptr,
    const int* __restrict__ sorted_src, const float* __restrict__ norm,
    const float* __restrict__ bias, const unsigned short* __restrict__ xcres,
    const _Float16* __restrict__ wf, unsigned short* __restrict__ xcout,
    float* __restrict__ xfull, _Float16* __restrict__ yout) {
    __shared__ _Float16 Blds[NCOLS * 128];        // 32 KB (128) / 16 KB (64)
    __shared__ _Float16 Alds[8 * 16 * 128];       // 32 KB, 4 KB per wave
    const int t = threadIdx.x;
    const int wave = t >> 6, lane = t & 63, quad = lane >> 4, l16 = lane & 15;

    // ---- B stage, then immediate barrier ----
#pragma unroll
    for (int i = 0; i < (NCOLS * 16) / GEMM_BLK; ++i) {
        int C = i * GEMM_BLK + t;
        int n = C >> 4, c = C & 15;
        const _Float16* gp = wf + ((size_t)n << 7) + ((c ^ (n & 7)) << 3);
        _Float16* lp = Blds + ((size_t)C << 3);
        __builtin_amdgcn_global_load_lds(
            (const __attribute__((address_space(1))) void*)gp,
            (__attribute__((address_space(3))) void*)lp, 16, 0, 0);
    }
    __syncthreads();

    const int wid = blockIdx.x * (GEMM_BLK / 64) + wave;
    const int rb0 = wid * 16;
    _Float16* Aw = Alds + (size_t)wave * 2048;
    const int g = quad, j = l16;

    // ---- gather + finalize: 4 batches x 4 nodes/wave, 16 lanes per node ----
    for (int tb = 0; tb < 4; ++tb) {
        const int n = rb0 + tb * 4 + g;
        const bool valid = n < NNODES;
        const int beg = valid ? row_ptr[n] : 0;
        const int dg = valid ? (row_ptr[n + 1] - beg) : 0;
        int dmax = dg;
        dmax = max(dmax, __shfl_xor(dmax, 16));
        dmax = max(dmax, __shfl_xor(dmax, 32));

        f32x8 acc = (f32x8){0.f, 0.f, 0.f, 0.f, 0.f, 0.f, 0.f, 0.f};
        for (int i = 0; i < dmax; i += 8) {
            int sarr[8];
#pragma unroll
            for (int u = 0; u < 8; ++u)
                sarr[u] = (i + u < dg) ? sorted_src[beg + i + u] : -1;
            half8 h[8];
#pragma unroll
            for (int u = 0; u < 8; ++u)
                if (sarr[u] >= 0)
                    h[u] = *(const half8*)(y + ((size_t)sarr[u] << 7) + j * 8);
#pragma unroll
            for (int u = 0; u < 8; ++u)
                if (sarr[u] >= 0) acc += __builtin_convertvector(h[u], f32x8);
        }

        half8 o;
        if (valid) {
            const half8 sh = *(const half8*)(y + ((size_t)n << 7) + j * 8);
            const f32x4 b0 = *(const f32x4*)(bias + j * 8);
            const f32x4 b1 = *(const f32x4*)(bias + j * 8 + 4);
            const float bb[8] = {b0[0], b0[1], b0[2], b0[3], b1[0], b1[1], b1[2], b1[3]};
            const float nm = norm[n];
            float v[8];
#pragma unroll
            for (int c = 0; c < 8; ++c) {
                float tv = (acc[c] + (float)sh[c]) * nm + bb[c];
                v[c] = tv >= 0.f ? tv : 0.01f * tv;
            }
            if (MODE == 1) {
                short8 hw = __builtin_nontemporal_load(
                    (const short8*)(xcres + ((size_t)n << 8) + j * 8));
                short8 lw = __builtin_nontemporal_load(
                    (const short8*)(xcres + ((size_t)n << 8) + 128 + j * 8));
#pragma unroll
                for (int c = 0; c < 8; ++c) {
                    float xr = bf2f((unsigned short)hw[c]) + bf2f((unsigned short)lw[c]);
                    v[c] = (xr + v[c]) * 0.5f;
                }
            }
            if (WOUT) {
                f32x4 o0 = (f32x4){v[0], v[1], v[2], v[3]};
                f32x4 o1 = (f32x4){v[4], v[5], v[6], v[7]};
                __builtin_nontemporal_store(o0, (f32x4*)(xfull + ((size_t)n << 7) + j * 8));
                __builtin_nontemporal_store(o1, (f32x4*)(xfull + ((size_t)n << 7) + j * 8 + 4));
            }
            if (WRXC) {
                short8 hi, lo;
#pragma unroll
                for (int c = 0; c < 8; ++c) {
                    unsigned short hv = f2bf(v[c]);
                    hi[c] = (short)hv;
                    lo[c] = (short)f2bf(v[c] - bf2f(hv));
                }
                *(short8*)(xcout + ((size_t)n << 8) + j * 8) = hi;
                *(short8*)(xcout + ((size_t)n << 8) + 128 + j * 8) = lo;
            }
#pragma unroll
            for (int c = 0; c < 8; ++c) o[c] = (_Float16)v[c];
        } else {
#pragma unroll
            for (int c = 0; c < 8; ++c) o[c] = (_Float16)0.f;
        }
        *(half8*)(Aw + (size_t)(tb * 4 + g) * 128 + j * 8) = o;
    }

    // ---- MFMA phase (A wave-local, B valid since barrier) ----
    const int sw = l16 & 7;
    half8 a0[4];
#pragma unroll
    for (int ck = 0; ck < 4; ++ck)
        a0[ck] = *(const half8*)(Aw + (size_t)l16 * 128 + ck * 32 + quad * 8);

    float nm0[4];
#pragma unroll
    for (int r = 0; r < 4; ++r) {
        int r0 = rb0 + quad * 4 + r;
        nm0[r] = norm[r0 < NNODES ? r0 : 0];
    }

#pragma unroll
    for (int nt = 0; nt < NCOLS / 16; ++nt) {
        const _Float16* bp = Blds + ((size_t)(nt * 16 + l16) << 7);
        half8 b[4];
#pragma unroll
        for (int ck = 0; ck < 4; ++ck)
            b[ck] = *(const half8*)(bp + (((ck * 4 + quad) ^ sw) << 3));
        f32x4 ac0 = (f32x4){0.f, 0.f, 0.f, 0.f};
#pragma unroll
        for (int ck = 0; ck < 4; ++ck)
            ac0 = __builtin_amdgcn_mfma_f32_16x16x32_f16(a0[ck], b[ck], ac0, 0, 0, 0);
        int col = nt * 16 + l16;
#pragma unroll
        for (int r = 0; r < 4; ++r) {
            int r0 = rb0 + quad * 4 + r;
            if (r0 < NNODES) yout[(size_t)r0 * NCOLS + col] = (_Float16)(ac0[r] * nm0[r]);
        }
    }
}

// ---------------- final gather (F=64, identity, fp16 y) ----------------
__global__ __launch_bounds__(256) void gather_fin64(
    const _Float16* __restrict__ y, const int* __restrict__ row_ptr,
    const int* __restrict__ sorted_src, const float* __restrict__ norm,
    const float* __restrict__ bias, float* __restrict__ out) {
    const int wave = threadIdx.x >> 6;
    const int lane = threadIdx.x & 63;
    const int g = lane >> 4, j = lane & 15;
    const int n = blockIdx.x * 16 + wave * 4 + g;
    const int beg = row_ptr[n];
    const int deg = row_ptr[n + 1] - beg;
    int dmax = deg;
    dmax = max(dmax, __shfl_xor(dmax, 16));
    dmax = max(dmax, __shfl_xor(dmax, 32));

    f32x4 acc = (f32x4){0.f, 0.f, 0.f, 0.f};
    for (int i = 0; i < dmax; i += 8) {
        int sarr[8];
#pragma unroll
        for (int u = 0; u < 8; ++u)
            sarr[u] = (i + u < deg) ? sorted_src[beg + i + u] : -1;
        half4 h[8];
#pragma unroll
        for (int u = 0; u < 8; ++u)
            if (sarr[u] >= 0)
                h[u] = *(const half4*)(y + ((size_t)sarr[u] << 6) + j * 4);
#pragma unroll
        for (int u = 0; u < 8; ++u)
            if (sarr[u] >= 0) acc += __builtin_convertvector(h[u], f32x4);
    }

    const half4 sh = *(const half4*)(y + ((size_t)n << 6) + j * 4);
    const f32x4 b = *(const f32x4*)(bias + j * 4);
    const float nm = norm[n];
    f32x4 o;
    o[0] = (acc[0] + (float)sh[0]) * nm + b[0];
    o[1] = (acc[1] + (float)sh[1]) * nm + b[1];
    o[2] = (acc[2] + (float)sh[2]) * nm + b[2];
    o[3] = (acc[3] + (float)sh[3]) * nm + b[3];
    __builtin_nontemporal_store(o, (f32x4*)(out + ((size_t)n << 6) + j * 4));
}

extern "C" void kernel_launch(void* const* d_in, const int* in_sizes, int n_in,
                              void* d_out, int out_size, void* d_ws, size_t ws_size,
                              hipStream_t stream) {
    const float* inputs = (const float*)d_in[0];
    const int* edges = (const int*)d_in[1];
    const int* src = edges;
    const int* dst = edges + NEDGES;
    const float* w_in  = (const float*)d_in[2];
    const float* b_in  = (const float*)d_in[3];
    const float* w1    = (const float*)d_in[4];
    const float* b1    = (const float*)d_in[5];
    const float* w2    = (const float*)d_in[6];
    const float* b2    = (const float*)d_in[7];
    const float* w_out = (const float*)d_in[8];
    const float* b_out = (const float*)d_in[9];

    float* out  = (float*)d_out;
    float* xout = out;                                // [N, 64]
    float* x    = out + (size_t)NNODES * OUTDIM;      // [N, 128] fp32 x (final only)

    char* p = (char*)d_ws;
    auto alloc = [&](size_t bytes) {
        char* r = p;
        p += (bytes + 63) & ~(size_t)63;
        return r;
    };
    int* deg        = (int*)alloc(NNODES * 4);
    int* epos       = (int*)alloc(NEDGES * 4);
    int* row_ptr    = (int*)alloc((NNODES + 1) * 4);
    int* bsum       = (int*)alloc(256 * 4);
    int* bofs       = (int*)alloc(256 * 4);
    int* sorted_src = (int*)alloc(NEDGES * 4);
    float* normb    = (float*)alloc(NNODES * 4);
    unsigned short* wT = (unsigned short*)alloc((size_t)32768 * 2);   // w_in hi/lo
    _Float16* w1f   = (_Float16*)alloc((size_t)6 * 16384 * 2);
    _Float16* w2f   = (_Float16*)alloc((size_t)6 * 16384 * 2);
    _Float16* woutf = (_Float16*)alloc((size_t)8192 * 2);
    unsigned short* xc_x = (unsigned short*)alloc((size_t)NPAD * 256 * 2);
    unsigned short* xc_in = (unsigned short*)alloc((size_t)NPAD * 256 * 2);
    _Float16* yA    = (_Float16*)alloc((size_t)NPAD * 128 * 2);
    _Float16* yB    = (_Float16*)alloc((size_t)NPAD * 128 * 2);

    // ---- CSR + norm + weight prep ----
    hipMemsetAsync(deg, 0, NNODES * sizeof(int), stream);
    count_kernel<<<(NEDGES + 255) / 256, 256, 0, stream>>>(dst, deg, epos);
    bsum_kernel<<<196, 256, 0, stream>>>(deg, bsum);
    bscan_kernel<<<1, 256, 0, stream>>>(bsum, bofs);
    emit_kernel<<<196, 256, 0, stream>>>(deg, bofs, row_ptr, normb);
    fill_kernel<<<(NEDGES + 255) / 256, 256, 0, stream>>>(src, dst, epos, row_ptr, sorted_src);
    prep_w_kernel<<<864, 256, 0, stream>>>(w_in, w1, w2, w_out, wT, w1f, w2f, woutf);

    // input layer: y0 = (inputs @ w_in)*norm (hi/lo, full precision A and B)
    split_x_kernel<<<(NPAD * 64) / 256, 256, 0, stream>>>(inputs, xc_in);
    gemm_bf_kernel<128><<<GEMM_GRID, GEMM_BLK, 0, stream>>>(xc_in, wT, normb, yA);

    // x1 = leaky(agg(y0)+b_in) -> xc_x state; fused with w1_0 GEMM -> yB
    fga_kernel<0, 128, true, false><<<GEMM_GRID, GEMM_BLK, 0, stream>>>(
        yA, row_ptr, sorted_src, normb, b_in, nullptr, w1f, xc_x, nullptr, yB);

    // 6 residual blocks: two fused kernels each
    for (int i = 0; i < 6; ++i) {
        // h = leaky(agg(yB)+b1_i); yA = (h @ w2_i)*norm
        fga_kernel<0, 128, false, false><<<GEMM_GRID, GEMM_BLK, 0, stream>>>(
            yB, row_ptr, sorted_src, normb, b1 + i * HDIM, nullptr,
            w2f + (size_t)i * 16384, nullptr, nullptr, yA);
        if (i < 5)
            // x = (x + leaky(agg(yA)+b2_i))/2 -> xc_x; yB = (x @ w1_{i+1})*norm
            fga_kernel<1, 128, true, false><<<GEMM_GRID, GEMM_BLK, 0, stream>>>(
                yA, row_ptr, sorted_src, normb, b2 + i * HDIM, xc_x,
                w1f + (size_t)(i + 1) * 16384, xc_x, nullptr, yB);
        else
            // final block: x -> fp32 out; yB = (x @ w_out)*norm (64 cols)
            fga_kernel<1, 64, false, true><<<GEMM_GRID, GEMM_BLK, 0, stream>>>(
                yA, row_ptr, sorted_src, normb, b2 + i * HDIM, xc_x,
                woutf, nullptr, x, yB);
    }

    // final aggregation (identity conv epilogue, 64 cols)
    gather_fin64<<<NNODES / 16, 256, 0, stream>>>(
        yB, row_ptr, sorted_src, normb, b_out, xout);
}

// Round 10
// 698.893 us; speedup vs baseline: 1.2033x; 1.0111x over previous
//
#include <hip/hip_runtime.h>

#define NNODES 50000
#define NPAD   50048   // 391 * 128
#define NEDGES 800000
#define HDIM 128
#define OUTDIM 64

#define GEMM_GRID 391
#define GEMM_BLK  512

typedef short short8 __attribute__((ext_vector_type(8)));
typedef _Float16 half8 __attribute__((ext_vector_type(8)));
typedef _Float16 half4 __attribute__((ext_vector_type(4)));
typedef float f32x4 __attribute__((ext_vector_type(4)));
typedef float f32x8 __attribute__((ext_vector_type(8)));

__device__ __forceinline__ unsigned short f2bf(float f) {
    unsigned int u = __builtin_bit_cast(unsigned int, f);
    unsigned int r = (u + 0x7FFFu + ((u >> 16) & 1u)) >> 16;
    return (unsigned short)r;
}
__device__ __forceinline__ float bf2f(unsigned short b) {
    unsigned int u = ((unsigned int)b) << 16;
    return __builtin_bit_cast(float, u);
}

// ---------------- CSR build ----------------
__global__ void count_kernel(const int* __restrict__ dst, int* __restrict__ deg,
                             int* __restrict__ epos) {
    int e = blockIdx.x * 256 + threadIdx.x;
    if (e < NEDGES) epos[e] = atomicAdd(&deg[dst[e]], 1);
}

__global__ __launch_bounds__(256) void bsum_kernel(const int* __restrict__ deg,
                                                   int* __restrict__ bsum) {
    __shared__ int red[256];
    int i = blockIdx.x * 256 + threadIdx.x;
    red[threadIdx.x] = (i < NNODES) ? deg[i] : 0;
    __syncthreads();
    for (int off = 128; off; off >>= 1) {
        if (threadIdx.x < off) red[threadIdx.x] += red[threadIdx.x + off];
        __syncthreads();
    }
    if (threadIdx.x == 0) bsum[blockIdx.x] = red[0];
}

__global__ __launch_bounds__(256) void bscan_kernel(const int* __restrict__ bsum,
                                                    int* __restrict__ bofs) {
    __shared__ int s[256];
    int t = threadIdx.x;
    int v = (t < 196) ? bsum[t] : 0;
    s[t] = v;
    __syncthreads();
    for (int off = 1; off < 256; off <<= 1) {
        int u = (t >= off) ? s[t - off] : 0;
        __syncthreads();
        s[t] += u;
        __syncthreads();
    }
    if (t < 196) bofs[t] = s[t] - v;  // exclusive
}

__global__ __launch_bounds__(256) void emit_kernel(
    const int* __restrict__ deg, const int* __restrict__ bofs,
    int* __restrict__ row_ptr, float* __restrict__ norm) {
    __shared__ int s[256];
    int t = threadIdx.x;
    int i = blockIdx.x * 256 + t;
    int v = (i < NNODES) ? deg[i] : 0;
    s[t] = v;
    __syncthreads();
    for (int off = 1; off < 256; off <<= 1) {
        int u = (t >= off) ? s[t - off] : 0;
        __syncthreads();
        s[t] += u;
        __syncthreads();
    }
    int excl = s[t] - v + bofs[blockIdx.x];
    if (i < NNODES) {
        row_ptr[i] = excl;
        norm[i] = rsqrtf(1.0f + (float)v);
    }
    if (i == NNODES - 1) row_ptr[NNODES] = NEDGES;
}

__global__ void fill_kernel(const int* __restrict__ src, const int* __restrict__ dst,
                            const int* __restrict__ epos, const int* __restrict__ row_ptr,
                            int* __restrict__ sorted_src) {
    int e = blockIdx.x * 256 + threadIdx.x;
    if (e < NEDGES) sorted_src[row_ptr[dst[e]] + epos[e]] = src[e];
}

// ---------------- weight prep ----------------
// wT: w_in bf16 hi/lo (input GEMM keeps full precision).
// w1f/w2f: per-block f16, layout [n][128] (k-major rows).
// woutf: w_out f16, [n=64][k=128].
__global__ __launch_bounds__(256) void prep_w_kernel(
    const float* __restrict__ w_in, const float* __restrict__ w1,
    const float* __restrict__ w2, const float* __restrict__ w_out,
    unsigned short* __restrict__ wT, _Float16* __restrict__ w1f,
    _Float16* __restrict__ w2f, _Float16* __restrict__ woutf) {
    int idx = blockIdx.x * 256 + threadIdx.x;  // total 221184 = 864*256
    if (idx < 16384) {
        int e = idx;
        int k = e >> 7, n = e & 127;
        float v = w_in[e];
        unsigned short h = f2bf(v);
        wT[(size_t)n * 256 + k] = h;
        wT[(size_t)n * 256 + 128 + k] = f2bf(v - bf2f(h));
    } else if (idx < 16384 + 98304) {
        int j = idx - 16384; int m = j >> 14; int e = j & 16383;
        int k = e >> 7, n = e & 127;
        w1f[(size_t)m * 16384 + n * 128 + k] = (_Float16)w1[((size_t)m << 14) + e];
    } else if (idx < 16384 + 196608) {
        int j = idx - 16384 - 98304; int m = j >> 14; int e = j & 16383;
        int k = e >> 7, n = e & 127;
        w2f[(size_t)m * 16384 + n * 128 + k] = (_Float16)w2[((size_t)m << 14) + e];
    } else {
        int e = idx - 212992;  // w_out: 8192 elements
        int k = e >> 6, n = e & 63;
        woutf[(size_t)n * 128 + k] = (_Float16)w_out[e];
    }
}

// ---------------- x split (input layer only) ----------------
__global__ __launch_bounds__(256) void split_x_kernel(
    const float* __restrict__ x, unsigned short* __restrict__ xc) {
    int gid = blockIdx.x * 256 + threadIdx.x;
    int row = gid >> 6;
    int kk = (gid & 63) * 2;
    float2 v = {0.f, 0.f};
    if (row < NNODES) v = *(const float2*)(x + (size_t)row * 128 + kk);
    unsigned short h0 = f2bf(v.x), h1 = f2bf(v.y);
    unsigned short l0 = f2bf(v.x - bf2f(h0)), l1 = f2bf(v.y - bf2f(h1));
    *(unsigned int*)(xc + (size_t)row * 256 + kk) =
        (unsigned int)h0 | ((unsigned int)h1 << 16);
    *(unsigned int*)(xc + (size_t)row * 256 + 128 + kk) =
        (unsigned int)l0 | ((unsigned int)l1 << 16);
}

// ---------------- bf16 hi/lo streaming MFMA GEMM (input layer only) --------
template <int NCOLS>
__global__ __launch_bounds__(GEMM_BLK) void gemm_bf_kernel(
    const unsigned short* __restrict__ xc, const unsigned short* __restrict__ wT,
    const float* __restrict__ norm, _Float16* __restrict__ y) {
    __shared__ unsigned short Blds[NCOLS * 256];
    const int t = threadIdx.x;
    const int wave = t >> 6, lane = t & 63, quad = lane >> 4, l16 = lane & 15;

    constexpr int NCH = NCOLS * 32;  // 16B chunks total
#pragma unroll
    for (int i = 0; i < NCH / GEMM_BLK; ++i) {
        int C = i * GEMM_BLK + t;
        int n = C >> 5, c = C & 31;
        const unsigned short* gp = wT + ((size_t)n << 8) + ((c ^ (n & 7)) << 3);
        unsigned short* lp = Blds + ((size_t)C << 3);
        __builtin_amdgcn_global_load_lds(
            (const __attribute__((address_space(1))) void*)gp,
            (__attribute__((address_space(3))) void*)lp, 16, 0, 0);
    }
    __syncthreads();

    const int wid = blockIdx.x * (GEMM_BLK / 64) + wave;
    const int sw = l16 & 7;
    const int rb0 = wid * 16;

    short8 a0[8];
    const unsigned short* ap0 = xc + ((size_t)(rb0 + l16) << 8) + quad * 8;
#pragma unroll
    for (int ck = 0; ck < 8; ++ck) a0[ck] = *(const short8*)(ap0 + ck * 32);

    float nm0[4];
#pragma unroll
    for (int r = 0; r < 4; ++r) {
        int r0 = rb0 + quad * 4 + r;
        nm0[r] = norm[r0 < NNODES ? r0 : 0];
    }

#pragma unroll
    for (int nt = 0; nt < NCOLS / 16; ++nt) {
        const unsigned short* bp = Blds + ((size_t)(nt * 16 + l16) << 8);
        short8 bh[4], bl[4];
#pragma unroll
        for (int ck = 0; ck < 4; ++ck) {
            bh[ck] = *(const short8*)(bp + (((ck * 4 + quad) ^ sw) << 3));
            bl[ck] = *(const short8*)(bp + (((16 + ck * 4 + quad) ^ sw) << 3));
        }
        f32x4 ac0 = (f32x4){0.f, 0.f, 0.f, 0.f};
#pragma unroll
        for (int ck = 0; ck < 4; ++ck) {
            ac0 = __builtin_amdgcn_mfma_f32_16x16x32_bf16(a0[ck], bh[ck], ac0, 0, 0, 0);
            ac0 = __builtin_amdgcn_mfma_f32_16x16x32_bf16(a0[ck], bl[ck], ac0, 0, 0, 0);
            ac0 = __builtin_amdgcn_mfma_f32_16x16x32_bf16(a0[4 + ck], bh[ck], ac0, 0, 0, 0);
        }
        int col = nt * 16 + l16;
#pragma unroll
        for (int r = 0; r < 4; ++r) {
            int r0 = rb0 + quad * 4 + r;
            if (r0 < NNODES) y[(size_t)r0 * NCOLS + col] = (_Float16)(ac0[r] * nm0[r]);
        }
    }
}

// -------- FUSED gather+finalize+f16 GEMM (fga) ------------------------------
// Gather loop 16-deep (64 rows in flight per wave: the gather is a pure
// latency x concurrency machine; r9 PMC showed 2.85 TB/s at 12 waves/CU,
// scaling with rows-in-flight). A-LDS chunk-XOR swizzled (r9: 750K bank
// conflicts from 256B row stride).
template <int MODE, int NCOLS, bool WRXC, bool WOUT>
__global__ __launch_bounds__(GEMM_BLK) void fga_kernel(
    const _Float16* __restrict__ y, const int* __restrict__ row_ptr,
    const int* __restrict__ sorted_src, const float* __restrict__ norm,
    const float* __restrict__ bias, const unsigned short* __restrict__ xcres,
    const _Float16* __restrict__ wf, unsigned short* __restrict__ xcout,
    float* __restrict__ xfull, _Float16* __restrict__ yout) {
    __shared__ _Float16 Blds[NCOLS * 128];        // 32 KB (128) / 16 KB (64)
    __shared__ _Float16 Alds[8 * 16 * 128];       // 32 KB, 4 KB per wave
    const int t = threadIdx.x;
    const int wave = t >> 6, lane = t & 63, quad = lane >> 4, l16 = lane & 15;

    // ---- B stage, then immediate barrier ----
#pragma unroll
    for (int i = 0; i < (NCOLS * 16) / GEMM_BLK; ++i) {
        int C = i * GEMM_BLK + t;
        int n = C >> 4, c = C & 15;
        const _Float16* gp = wf + ((size_t)n << 7) + ((c ^ (n & 7)) << 3);
        _Float16* lp = Blds + ((size_t)C << 3);
        __builtin_amdgcn_global_load_lds(
            (const __attribute__((address_space(1))) void*)gp,
            (__attribute__((address_space(3))) void*)lp, 16, 0, 0);
    }
    __syncthreads();

    const int wid = blockIdx.x * (GEMM_BLK / 64) + wave;
    const int rb0 = wid * 16;
    _Float16* Aw = Alds + (size_t)wave * 2048;
    const int g = quad, j = l16;

    // ---- gather + finalize: 4 batches x 4 nodes/wave, 16 lanes per node ----
    for (int tb = 0; tb < 4; ++tb) {
        const int row = tb * 4 + g;
        const int n = rb0 + row;
        const bool valid = n < NNODES;
        const int beg = valid ? row_ptr[n] : 0;
        const int dg = valid ? (row_ptr[n + 1] - beg) : 0;
        int dmax = dg;
        dmax = max(dmax, __shfl_xor(dmax, 16));
        dmax = max(dmax, __shfl_xor(dmax, 32));

        f32x8 acc = (f32x8){0.f, 0.f, 0.f, 0.f, 0.f, 0.f, 0.f, 0.f};
        for (int i = 0; i < dmax; i += 16) {
            int sarr[16];
#pragma unroll
            for (int u = 0; u < 16; ++u)
                sarr[u] = (i + u < dg) ? sorted_src[beg + i + u] : -1;
            half8 h[16];
#pragma unroll
            for (int u = 0; u < 16; ++u)
                if (sarr[u] >= 0)
                    h[u] = *(const half8*)(y + ((size_t)sarr[u] << 7) + j * 8);
#pragma unroll
            for (int u = 0; u < 16; ++u)
                if (sarr[u] >= 0) acc += __builtin_convertvector(h[u], f32x8);
        }

        half8 o;
        if (valid) {
            const half8 sh = *(const half8*)(y + ((size_t)n << 7) + j * 8);
            const f32x4 b0 = *(const f32x4*)(bias + j * 8);
            const f32x4 b1 = *(const f32x4*)(bias + j * 8 + 4);
            const float bb[8] = {b0[0], b0[1], b0[2], b0[3], b1[0], b1[1], b1[2], b1[3]};
            const float nm = norm[n];
            float v[8];
#pragma unroll
            for (int c = 0; c < 8; ++c) {
                float tv = (acc[c] + (float)sh[c]) * nm + bb[c];
                v[c] = tv >= 0.f ? tv : 0.01f * tv;
            }
            if (MODE == 1) {
                short8 hw = __builtin_nontemporal_load(
                    (const short8*)(xcres + ((size_t)n << 8) + j * 8));
                short8 lw = __builtin_nontemporal_load(
                    (const short8*)(xcres + ((size_t)n << 8) + 128 + j * 8));
#pragma unroll
                for (int c = 0; c < 8; ++c) {
                    float xr = bf2f((unsigned short)hw[c]) + bf2f((unsigned short)lw[c]);
                    v[c] = (xr + v[c]) * 0.5f;
                }
            }
            if (WOUT) {
                f32x4 o0 = (f32x4){v[0], v[1], v[2], v[3]};
                f32x4 o1 = (f32x4){v[4], v[5], v[6], v[7]};
                __builtin_nontemporal_store(o0, (f32x4*)(xfull + ((size_t)n << 7) + j * 8));
                __builtin_nontemporal_store(o1, (f32x4*)(xfull + ((size_t)n << 7) + j * 8 + 4));
            }
            if (WRXC) {
                short8 hi, lo;
#pragma unroll
                for (int c = 0; c < 8; ++c) {
                    unsigned short hv = f2bf(v[c]);
                    hi[c] = (short)hv;
                    lo[c] = (short)f2bf(v[c] - bf2f(hv));
                }
                *(short8*)(xcout + ((size_t)n << 8) + j * 8) = hi;
                *(short8*)(xcout + ((size_t)n << 8) + 128 + j * 8) = lo;
            }
#pragma unroll
            for (int c = 0; c < 8; ++c) o[c] = (_Float16)v[c];
        } else {
#pragma unroll
            for (int c = 0; c < 8; ++c) o[c] = (_Float16)0.f;
        }
        // chunk-XOR swizzled A write: row stride 256B would alias banks
        *(half8*)(Aw + ((size_t)row * 16 + (j ^ (row & 7))) * 8) = o;
    }

    // ---- MFMA phase (A wave-local, B valid since barrier) ----
    const int sw = l16 & 7;
    half8 a0[4];
#pragma unroll
    for (int ck = 0; ck < 4; ++ck)
        a0[ck] = *(const half8*)(Aw + ((size_t)l16 * 16 + ((ck * 4 + quad) ^ (l16 & 7))) * 8);

    float nm0[4];
#pragma unroll
    for (int r = 0; r < 4; ++r) {
        int r0 = rb0 + quad * 4 + r;
        nm0[r] = norm[r0 < NNODES ? r0 : 0];
    }

#pragma unroll
    for (int nt = 0; nt < NCOLS / 16; ++nt) {
        const _Float16* bp = Blds + ((size_t)(nt * 16 + l16) << 7);
        half8 b[4];
#pragma unroll
        for (int ck = 0; ck < 4; ++ck)
            b[ck] = *(const half8*)(bp + (((ck * 4 + quad) ^ sw) << 3));
        f32x4 ac0 = (f32x4){0.f, 0.f, 0.f, 0.f};
#pragma unroll
        for (int ck = 0; ck < 4; ++ck)
            ac0 = __builtin_amdgcn_mfma_f32_16x16x32_f16(a0[ck], b[ck], ac0, 0, 0, 0);
        int col = nt * 16 + l16;
#pragma unroll
        for (int r = 0; r < 4; ++r) {
            int r0 = rb0 + quad * 4 + r;
            if (r0 < NNODES) yout[(size_t)r0 * NCOLS + col] = (_Float16)(ac0[r] * nm0[r]);
        }
    }
}

// ---------------- final gather (F=64, identity, fp16 y) ----------------
__global__ __launch_bounds__(256) void gather_fin64(
    const _Float16* __restrict__ y, const int* __restrict__ row_ptr,
    const int* __restrict__ sorted_src, const float* __restrict__ norm,
    const float* __restrict__ bias, float* __restrict__ out) {
    const int wave = threadIdx.x >> 6;
    const int lane = threadIdx.x & 63;
    const int g = lane >> 4, j = lane & 15;
    const int n = blockIdx.x * 16 + wave * 4 + g;
    const int beg = row_ptr[n];
    const int deg = row_ptr[n + 1] - beg;
    int dmax = deg;
    dmax = max(dmax, __shfl_xor(dmax, 16));
    dmax = max(dmax, __shfl_xor(dmax, 32));

    f32x4 acc = (f32x4){0.f, 0.f, 0.f, 0.f};
    for (int i = 0; i < dmax; i += 16) {
        int sarr[16];
#pragma unroll
        for (int u = 0; u < 16; ++u)
            sarr[u] = (i + u < deg) ? sorted_src[beg + i + u] : -1;
        half4 h[16];
#pragma unroll
        for (int u = 0; u < 16; ++u)
            if (sarr[u] >= 0)
                h[u] = *(const half4*)(y + ((size_t)sarr[u] << 6) + j * 4);
#pragma unroll
        for (int u = 0; u < 16; ++u)
            if (sarr[u] >= 0) acc += __builtin_convertvector(h[u], f32x4);
    }

    const half4 sh = *(const half4*)(y + ((size_t)n << 6) + j * 4);
    const f32x4 b = *(const f32x4*)(bias + j * 4);
    const float nm = norm[n];
    f32x4 o;
    o[0] = (acc[0] + (float)sh[0]) * nm + b[0];
    o[1] = (acc[1] + (float)sh[1]) * nm + b[1];
    o[2] = (acc[2] + (float)sh[2]) * nm + b[2];
    o[3] = (acc[3] + (float)sh[3]) * nm + b[3];
    __builtin_nontemporal_store(o, (f32x4*)(out + ((size_t)n << 6) + j * 4));
}

extern "C" void kernel_launch(void* const* d_in, const int* in_sizes, int n_in,
                              void* d_out, int out_size, void* d_ws, size_t ws_size,
                              hipStream_t stream) {
    const float* inputs = (const float*)d_in[0];
    const int* edges = (const int*)d_in[1];
    const int* src = edges;
    const int* dst = edges + NEDGES;
    const float* w_in  = (const float*)d_in[2];
    const float* b_in  = (const float*)d_in[3];
    const float* w1    = (const float*)d_in[4];
    const float* b1    = (const float*)d_in[5];
    const float* w2    = (const float*)d_in[6];
    const float* b2    = (const float*)d_in[7];
    const float* w_out = (const float*)d_in[8];
    const float* b_out = (const float*)d_in[9];

    float* out  = (float*)d_out;
    float* xout = out;                                // [N, 64]
    float* x    = out + (size_t)NNODES * OUTDIM;      // [N, 128] fp32 x (final only)

    char* p = (char*)d_ws;
    auto alloc = [&](size_t bytes) {
        char* r = p;
        p += (bytes + 63) & ~(size_t)63;
        return r;
    };
    int* deg        = (int*)alloc(NNODES * 4);
    int* epos       = (int*)alloc(NEDGES * 4);
    int* row_ptr    = (int*)alloc((NNODES + 1) * 4);
    int* bsum       = (int*)alloc(256 * 4);
    int* bofs       = (int*)alloc(256 * 4);
    int* sorted_src = (int*)alloc(NEDGES * 4);
    float* normb    = (float*)alloc(NNODES * 4);
    unsigned short* wT = (unsigned short*)alloc((size_t)32768 * 2);   // w_in hi/lo
    _Float16* w1f   = (_Float16*)alloc((size_t)6 * 16384 * 2);
    _Float16* w2f   = (_Float16*)alloc((size_t)6 * 16384 * 2);
    _Float16* woutf = (_Float16*)alloc((size_t)8192 * 2);
    unsigned short* xc_x = (unsigned short*)alloc((size_t)NPAD * 256 * 2);
    unsigned short* xc_in = (unsigned short*)alloc((size_t)NPAD * 256 * 2);
    _Float16* yA    = (_Float16*)alloc((size_t)NPAD * 128 * 2);
    _Float16* yB    = (_Float16*)alloc((size_t)NPAD * 128 * 2);

    // ---- CSR + norm + weight prep ----
    hipMemsetAsync(deg, 0, NNODES * sizeof(int), stream);
    count_kernel<<<(NEDGES + 255) / 256, 256, 0, stream>>>(dst, deg, epos);
    bsum_kernel<<<196, 256, 0, stream>>>(deg, bsum);
    bscan_kernel<<<1, 256, 0, stream>>>(bsum, bofs);
    emit_kernel<<<196, 256, 0, stream>>>(deg, bofs, row_ptr, normb);
    fill_kernel<<<(NEDGES + 255) / 256, 256, 0, stream>>>(src, dst, epos, row_ptr, sorted_src);
    prep_w_kernel<<<864, 256, 0, stream>>>(w_in, w1, w2, w_out, wT, w1f, w2f, woutf);

    // input layer: y0 = (inputs @ w_in)*norm (hi/lo, full precision A and B)
    split_x_kernel<<<(NPAD * 64) / 256, 256, 0, stream>>>(inputs, xc_in);
    gemm_bf_kernel<128><<<GEMM_GRID, GEMM_BLK, 0, stream>>>(xc_in, wT, normb, yA);

    // x1 = leaky(agg(y0)+b_in) -> xc_x state; fused with w1_0 GEMM -> yB
    fga_kernel<0, 128, true, false><<<GEMM_GRID, GEMM_BLK, 0, stream>>>(
        yA, row_ptr, sorted_src, normb, b_in, nullptr, w1f, xc_x, nullptr, yB);

    // 6 residual blocks: two fused kernels each
    for (int i = 0; i < 6; ++i) {
        // h = leaky(agg(yB)+b1_i); yA = (h @ w2_i)*norm
        fga_kernel<0, 128, false, false><<<GEMM_GRID, GEMM_BLK, 0, stream>>>(
            yB, row_ptr, sorted_src, normb, b1 + i * HDIM, nullptr,
            w2f + (size_t)i * 16384, nullptr, nullptr, yA);
        if (i < 5)
            // x = (x + leaky(agg(yA)+b2_i))/2 -> xc_x; yB = (x @ w1_{i+1})*norm
            fga_kernel<1, 128, true, false><<<GEMM_GRID, GEMM_BLK, 0, stream>>>(
                yA, row_ptr, sorted_src, normb, b2 + i * HDIM, xc_x,
                w1f + (size_t)(i + 1) * 16384, xc_x, nullptr, yB);
        else
            // final block: x -> fp32 out; yB = (x @ w_out)*norm (64 cols)
            fga_kernel<1, 64, false, true><<<GEMM_GRID, GEMM_BLK, 0, stream>>>(
                yA, row_ptr, sorted_src, normb, b2 + i * HDIM, xc_x,
                woutf, nullptr, x, yB);
    }

    // final aggregation (identity conv epilogue, 64 cols)
    gather_fin64<<<NNODES / 16, 256, 0, stream>>>(
        yB, row_ptr, sorted_src, normb, b_out, xout);
}

// Round 11
// 698.340 us; speedup vs baseline: 1.2043x; 1.0008x over previous
//
#include <hip/hip_runtime.h>

#define NNODES 50000
#define NPAD   50048   // 391 * 128
#define NEDGES 800000
#define HDIM 128
#define OUTDIM 64

#define GEMM_GRID 391
#define GEMM_BLK  512

typedef short short8 __attribute__((ext_vector_type(8)));
typedef _Float16 half8 __attribute__((ext_vector_type(8)));
typedef _Float16 half4 __attribute__((ext_vector_type(4)));
typedef float f32x4 __attribute__((ext_vector_type(4)));
typedef float f32x8 __attribute__((ext_vector_type(8)));

__device__ __forceinline__ unsigned short f2bf(float f) {
    unsigned int u = __builtin_bit_cast(unsigned int, f);
    unsigned int r = (u + 0x7FFFu + ((u >> 16) & 1u)) >> 16;
    return (unsigned short)r;
}
__device__ __forceinline__ float bf2f(unsigned short b) {
    unsigned int u = ((unsigned int)b) << 16;
    return __builtin_bit_cast(float, u);
}

// ---------------- CSR build ----------------
__global__ void count_kernel(const int* __restrict__ dst, int* __restrict__ deg,
                             int* __restrict__ epos) {
    int e = blockIdx.x * 256 + threadIdx.x;
    if (e < NEDGES) epos[e] = atomicAdd(&deg[dst[e]], 1);
}

__global__ __launch_bounds__(256) void bsum_kernel(const int* __restrict__ deg,
                                                   int* __restrict__ bsum) {
    __shared__ int red[256];
    int i = blockIdx.x * 256 + threadIdx.x;
    red[threadIdx.x] = (i < NNODES) ? deg[i] : 0;
    __syncthreads();
    for (int off = 128; off; off >>= 1) {
        if (threadIdx.x < off) red[threadIdx.x] += red[threadIdx.x + off];
        __syncthreads();
    }
    if (threadIdx.x == 0) bsum[blockIdx.x] = red[0];
}

__global__ __launch_bounds__(256) void bscan_kernel(const int* __restrict__ bsum,
                                                    int* __restrict__ bofs) {
    __shared__ int s[256];
    int t = threadIdx.x;
    int v = (t < 196) ? bsum[t] : 0;
    s[t] = v;
    __syncthreads();
    for (int off = 1; off < 256; off <<= 1) {
        int u = (t >= off) ? s[t - off] : 0;
        __syncthreads();
        s[t] += u;
        __syncthreads();
    }
    if (t < 196) bofs[t] = s[t] - v;  // exclusive
}

__global__ __launch_bounds__(256) void emit_kernel(
    const int* __restrict__ deg, const int* __restrict__ bofs,
    int* __restrict__ row_ptr, float* __restrict__ norm) {
    __shared__ int s[256];
    int t = threadIdx.x;
    int i = blockIdx.x * 256 + t;
    int v = (i < NNODES) ? deg[i] : 0;
    s[t] = v;
    __syncthreads();
    for (int off = 1; off < 256; off <<= 1) {
        int u = (t >= off) ? s[t - off] : 0;
        __syncthreads();
        s[t] += u;
        __syncthreads();
    }
    int excl = s[t] - v + bofs[blockIdx.x];
    if (i < NNODES) {
        row_ptr[i] = excl;
        norm[i] = rsqrtf(1.0f + (float)v);
    }
    if (i == NNODES - 1) row_ptr[NNODES] = NEDGES;
}

__global__ void fill_kernel(const int* __restrict__ src, const int* __restrict__ dst,
                            const int* __restrict__ epos, const int* __restrict__ row_ptr,
                            int* __restrict__ sorted_src) {
    int e = blockIdx.x * 256 + threadIdx.x;
    if (e < NEDGES) sorted_src[row_ptr[dst[e]] + epos[e]] = src[e];
}

// ---------------- weight prep ----------------
// wT: w_in bf16 hi/lo (input GEMM keeps full precision).
// w1f/w2f: per-block f16, layout [n][128] (k-major rows).
// woutf: w_out f16, [n=64][k=128].
__global__ __launch_bounds__(256) void prep_w_kernel(
    const float* __restrict__ w_in, const float* __restrict__ w1,
    const float* __restrict__ w2, const float* __restrict__ w_out,
    unsigned short* __restrict__ wT, _Float16* __restrict__ w1f,
    _Float16* __restrict__ w2f, _Float16* __restrict__ woutf) {
    int idx = blockIdx.x * 256 + threadIdx.x;  // total 221184 = 864*256
    if (idx < 16384) {
        int e = idx;
        int k = e >> 7, n = e & 127;
        float v = w_in[e];
        unsigned short h = f2bf(v);
        wT[(size_t)n * 256 + k] = h;
        wT[(size_t)n * 256 + 128 + k] = f2bf(v - bf2f(h));
    } else if (idx < 16384 + 98304) {
        int j = idx - 16384; int m = j >> 14; int e = j & 16383;
        int k = e >> 7, n = e & 127;
        w1f[(size_t)m * 16384 + n * 128 + k] = (_Float16)w1[((size_t)m << 14) + e];
    } else if (idx < 16384 + 196608) {
        int j = idx - 16384 - 98304; int m = j >> 14; int e = j & 16383;
        int k = e >> 7, n = e & 127;
        w2f[(size_t)m * 16384 + n * 128 + k] = (_Float16)w2[((size_t)m << 14) + e];
    } else {
        int e = idx - 212992;  // w_out: 8192 elements
        int k = e >> 6, n = e & 63;
        woutf[(size_t)n * 128 + k] = (_Float16)w_out[e];
    }
}

// ---------------- x split (input layer only) ----------------
__global__ __launch_bounds__(256) void split_x_kernel(
    const float* __restrict__ x, unsigned short* __restrict__ xc) {
    int gid = blockIdx.x * 256 + threadIdx.x;
    int row = gid >> 6;
    int kk = (gid & 63) * 2;
    float2 v = {0.f, 0.f};
    if (row < NNODES) v = *(const float2*)(x + (size_t)row * 128 + kk);
    unsigned short h0 = f2bf(v.x), h1 = f2bf(v.y);
    unsigned short l0 = f2bf(v.x - bf2f(h0)), l1 = f2bf(v.y - bf2f(h1));
    *(unsigned int*)(xc + (size_t)row * 256 + kk) =
        (unsigned int)h0 | ((unsigned int)h1 << 16);
    *(unsigned int*)(xc + (size_t)row * 256 + 128 + kk) =
        (unsigned int)l0 | ((unsigned int)l1 << 16);
}

// ---------------- bf16 hi/lo streaming MFMA GEMM (input layer only) --------
template <int NCOLS>
__global__ __launch_bounds__(GEMM_BLK) void gemm_bf_kernel(
    const unsigned short* __restrict__ xc, const unsigned short* __restrict__ wT,
    const float* __restrict__ norm, _Float16* __restrict__ y) {
    __shared__ unsigned short Blds[NCOLS * 256];
    const int t = threadIdx.x;
    const int wave = t >> 6, lane = t & 63, quad = lane >> 4, l16 = lane & 15;

    constexpr int NCH = NCOLS * 32;  // 16B chunks total
#pragma unroll
    for (int i = 0; i < NCH / GEMM_BLK; ++i) {
        int C = i * GEMM_BLK + t;
        int n = C >> 5, c = C & 31;
        const unsigned short* gp = wT + ((size_t)n << 8) + ((c ^ (n & 7)) << 3);
        unsigned short* lp = Blds + ((size_t)C << 3);
        __builtin_amdgcn_global_load_lds(
            (const __attribute__((address_space(1))) void*)gp,
            (__attribute__((address_space(3))) void*)lp, 16, 0, 0);
    }
    __syncthreads();

    const int wid = blockIdx.x * (GEMM_BLK / 64) + wave;
    const int sw = l16 & 7;
    const int rb0 = wid * 16;

    short8 a0[8];
    const unsigned short* ap0 = xc + ((size_t)(rb0 + l16) << 8) + quad * 8;
#pragma unroll
    for (int ck = 0; ck < 8; ++ck) a0[ck] = *(const short8*)(ap0 + ck * 32);

    float nm0[4];
#pragma unroll
    for (int r = 0; r < 4; ++r) {
        int r0 = rb0 + quad * 4 + r;
        nm0[r] = norm[r0 < NNODES ? r0 : 0];
    }

#pragma unroll
    for (int nt = 0; nt < NCOLS / 16; ++nt) {
        const unsigned short* bp = Blds + ((size_t)(nt * 16 + l16) << 8);
        short8 bh[4], bl[4];
#pragma unroll
        for (int ck = 0; ck < 4; ++ck) {
            bh[ck] = *(const short8*)(bp + (((ck * 4 + quad) ^ sw) << 3));
            bl[ck] = *(const short8*)(bp + (((16 + ck * 4 + quad) ^ sw) << 3));
        }
        f32x4 ac0 = (f32x4){0.f, 0.f, 0.f, 0.f};
#pragma unroll
        for (int ck = 0; ck < 4; ++ck) {
            ac0 = __builtin_amdgcn_mfma_f32_16x16x32_bf16(a0[ck], bh[ck], ac0, 0, 0, 0);
            ac0 = __builtin_amdgcn_mfma_f32_16x16x32_bf16(a0[ck], bl[ck], ac0, 0, 0, 0);
            ac0 = __builtin_amdgcn_mfma_f32_16x16x32_bf16(a0[4 + ck], bh[ck], ac0, 0, 0, 0);
        }
        int col = nt * 16 + l16;
#pragma unroll
        for (int r = 0; r < 4; ++r) {
            int r0 = rb0 + quad * 4 + r;
            if (r0 < NNODES) y[(size_t)r0 * NCOLS + col] = (_Float16)(ac0[r] * nm0[r]);
        }
    }
}

// -------- FUSED gather+finalize+f16 GEMM (fga) ------------------------------
// __launch_bounds__(512, 4): 4 waves/SIMD = 16 waves/CU (exactly the 2
// blocks/CU the 64KB LDS allows) -> VGPR cap 128. r10 PMC showed VGPR=64,
// which cannot hold the 16-deep row batch (16 x half8 = 64 VGPR alone) —
// the compiler was strip-mining the loads, defeating the MLP. This change
// is occupancy-neutral and lets the full batch stay in flight.
template <int MODE, int NCOLS, bool WRXC, bool WOUT>
__global__ __launch_bounds__(GEMM_BLK, 4) void fga_kernel(
    const _Float16* __restrict__ y, const int* __restrict__ row_ptr,
    const int* __restrict__ sorted_src, const float* __restrict__ norm,
    const float* __restrict__ bias, const unsigned short* __restrict__ xcres,
    const _Float16* __restrict__ wf, unsigned short* __restrict__ xcout,
    float* __restrict__ xfull, _Float16* __restrict__ yout) {
    __shared__ _Float16 Blds[NCOLS * 128];        // 32 KB (128) / 16 KB (64)
    __shared__ _Float16 Alds[8 * 16 * 128];       // 32 KB, 4 KB per wave
    const int t = threadIdx.x;
    const int wave = t >> 6, lane = t & 63, quad = lane >> 4, l16 = lane & 15;

    // ---- B stage, then immediate barrier ----
#pragma unroll
    for (int i = 0; i < (NCOLS * 16) / GEMM_BLK; ++i) {
        int C = i * GEMM_BLK + t;
        int n = C >> 4, c = C & 15;
        const _Float16* gp = wf + ((size_t)n << 7) + ((c ^ (n & 7)) << 3);
        _Float16* lp = Blds + ((size_t)C << 3);
        __builtin_amdgcn_global_load_lds(
            (const __attribute__((address_space(1))) void*)gp,
            (__attribute__((address_space(3))) void*)lp, 16, 0, 0);
    }
    __syncthreads();

    const int wid = blockIdx.x * (GEMM_BLK / 64) + wave;
    const int rb0 = wid * 16;
    _Float16* Aw = Alds + (size_t)wave * 2048;
    const int g = quad, j = l16;

    // ---- gather + finalize: 4 batches x 4 nodes/wave, 16 lanes per node ----
    for (int tb = 0; tb < 4; ++tb) {
        const int row = tb * 4 + g;
        const int n = rb0 + row;
        const bool valid = n < NNODES;
        const int beg = valid ? row_ptr[n] : 0;
        const int dg = valid ? (row_ptr[n + 1] - beg) : 0;
        int dmax = dg;
        dmax = max(dmax, __shfl_xor(dmax, 16));
        dmax = max(dmax, __shfl_xor(dmax, 32));

        f32x8 acc = (f32x8){0.f, 0.f, 0.f, 0.f, 0.f, 0.f, 0.f, 0.f};
        for (int i = 0; i < dmax; i += 16) {
            int sarr[16];
#pragma unroll
            for (int u = 0; u < 16; ++u)
                sarr[u] = (i + u < dg) ? sorted_src[beg + i + u] : -1;
            half8 h[16];
#pragma unroll
            for (int u = 0; u < 16; ++u)
                if (sarr[u] >= 0)
                    h[u] = *(const half8*)(y + ((size_t)sarr[u] << 7) + j * 8);
#pragma unroll
            for (int u = 0; u < 16; ++u)
                if (sarr[u] >= 0) acc += __builtin_convertvector(h[u], f32x8);
        }

        half8 o;
        if (valid) {
            const half8 sh = *(const half8*)(y + ((size_t)n << 7) + j * 8);
            const f32x4 b0 = *(const f32x4*)(bias + j * 8);
            const f32x4 b1 = *(const f32x4*)(bias + j * 8 + 4);
            const float bb[8] = {b0[0], b0[1], b0[2], b0[3], b1[0], b1[1], b1[2], b1[3]};
            const float nm = norm[n];
            float v[8];
#pragma unroll
            for (int c = 0; c < 8; ++c) {
                float tv = (acc[c] + (float)sh[c]) * nm + bb[c];
                v[c] = tv >= 0.f ? tv : 0.01f * tv;
            }
            if (MODE == 1) {
                short8 hw = __builtin_nontemporal_load(
                    (const short8*)(xcres + ((size_t)n << 8) + j * 8));
                short8 lw = __builtin_nontemporal_load(
                    (const short8*)(xcres + ((size_t)n << 8) + 128 + j * 8));
#pragma unroll
                for (int c = 0; c < 8; ++c) {
                    float xr = bf2f((unsigned short)hw[c]) + bf2f((unsigned short)lw[c]);
                    v[c] = (xr + v[c]) * 0.5f;
                }
            }
            if (WOUT) {
                f32x4 o0 = (f32x4){v[0], v[1], v[2], v[3]};
                f32x4 o1 = (f32x4){v[4], v[5], v[6], v[7]};
                __builtin_nontemporal_store(o0, (f32x4*)(xfull + ((size_t)n << 7) + j * 8));
                __builtin_nontemporal_store(o1, (f32x4*)(xfull + ((size_t)n << 7) + j * 8 + 4));
            }
            if (WRXC) {
                short8 hi, lo;
#pragma unroll
                for (int c = 0; c < 8; ++c) {
                    unsigned short hv = f2bf(v[c]);
                    hi[c] = (short)hv;
                    lo[c] = (short)f2bf(v[c] - bf2f(hv));
                }
                *(short8*)(xcout + ((size_t)n << 8) + j * 8) = hi;
                *(short8*)(xcout + ((size_t)n << 8) + 128 + j * 8) = lo;
            }
#pragma unroll
            for (int c = 0; c < 8; ++c) o[c] = (_Float16)v[c];
        } else {
#pragma unroll
            for (int c = 0; c < 8; ++c) o[c] = (_Float16)0.f;
        }
        // chunk-XOR swizzled A write: row stride 256B would alias banks
        *(half8*)(Aw + ((size_t)row * 16 + (j ^ (row & 7))) * 8) = o;
    }

    // ---- MFMA phase (A wave-local, B valid since barrier) ----
    const int sw = l16 & 7;
    half8 a0[4];
#pragma unroll
    for (int ck = 0; ck < 4; ++ck)
        a0[ck] = *(const half8*)(Aw + ((size_t)l16 * 16 + ((ck * 4 + quad) ^ (l16 & 7))) * 8);

    float nm0[4];
#pragma unroll
    for (int r = 0; r < 4; ++r) {
        int r0 = rb0 + quad * 4 + r;
        nm0[r] = norm[r0 < NNODES ? r0 : 0];
    }

#pragma unroll
    for (int nt = 0; nt < NCOLS / 16; ++nt) {
        const _Float16* bp = Blds + ((size_t)(nt * 16 + l16) << 7);
        half8 b[4];
#pragma unroll
        for (int ck = 0; ck < 4; ++ck)
            b[ck] = *(const half8*)(bp + (((ck * 4 + quad) ^ sw) << 3));
        f32x4 ac0 = (f32x4){0.f, 0.f, 0.f, 0.f};
#pragma unroll
        for (int ck = 0; ck < 4; ++ck)
            ac0 = __builtin_amdgcn_mfma_f32_16x16x32_f16(a0[ck], b[ck], ac0, 0, 0, 0);
        int col = nt * 16 + l16;
#pragma unroll
        for (int r = 0; r < 4; ++r) {
            int r0 = rb0 + quad * 4 + r;
            if (r0 < NNODES) yout[(size_t)r0 * NCOLS + col] = (_Float16)(ac0[r] * nm0[r]);
        }
    }
}

// ---------------- final gather (F=64, identity, fp16 y) ----------------
__global__ __launch_bounds__(256) void gather_fin64(
    const _Float16* __restrict__ y, const int* __restrict__ row_ptr,
    const int* __restrict__ sorted_src, const float* __restrict__ norm,
    const float* __restrict__ bias, float* __restrict__ out) {
    const int wave = threadIdx.x >> 6;
    const int lane = threadIdx.x & 63;
    const int g = lane >> 4, j = lane & 15;
    const int n = blockIdx.x * 16 + wave * 4 + g;
    const int beg = row_ptr[n];
    const int deg = row_ptr[n + 1] - beg;
    int dmax = deg;
    dmax = max(dmax, __shfl_xor(dmax, 16));
    dmax = max(dmax, __shfl_xor(dmax, 32));

    f32x4 acc = (f32x4){0.f, 0.f, 0.f, 0.f};
    for (int i = 0; i < dmax; i += 16) {
        int sarr[16];
#pragma unroll
        for (int u = 0; u < 16; ++u)
            sarr[u] = (i + u < deg) ? sorted_src[beg + i + u] : -1;
        half4 h[16];
#pragma unroll
        for (int u = 0; u < 16; ++u)
            if (sarr[u] >= 0)
                h[u] = *(const half4*)(y + ((size_t)sarr[u] << 6) + j * 4);
#pragma unroll
        for (int u = 0; u < 16; ++u)
            if (sarr[u] >= 0) acc += __builtin_convertvector(h[u], f32x4);
    }

    const half4 sh = *(const half4*)(y + ((size_t)n << 6) + j * 4);
    const f32x4 b = *(const f32x4*)(bias + j * 4);
    const float nm = norm[n];
    f32x4 o;
    o[0] = (acc[0] + (float)sh[0]) * nm + b[0];
    o[1] = (acc[1] + (float)sh[1]) * nm + b[1];
    o[2] = (acc[2] + (float)sh[2]) * nm + b[2];
    o[3] = (acc[3] + (float)sh[3]) * nm + b[3];
    __builtin_nontemporal_store(o, (f32x4*)(out + ((size_t)n << 6) + j * 4));
}

extern "C" void kernel_launch(void* const* d_in, const int* in_sizes, int n_in,
                              void* d_out, int out_size, void* d_ws, size_t ws_size,
                              hipStream_t stream) {
    const float* inputs = (const float*)d_in[0];
    const int* edges = (const int*)d_in[1];
    const int* src = edges;
    const int* dst = edges + NEDGES;
    const float* w_in  = (const float*)d_in[2];
    const float* b_in  = (const float*)d_in[3];
    const float* w1    = (const float*)d_in[4];
    const float* b1    = (const float*)d_in[5];
    const float* w2    = (const float*)d_in[6];
    const float* b2    = (const float*)d_in[7];
    const float* w_out = (const float*)d_in[8];
    const float* b_out = (const float*)d_in[9];

    float* out  = (float*)d_out;
    float* xout = out;                                // [N, 64]
    float* x    = out + (size_t)NNODES * OUTDIM;      // [N, 128] fp32 x (final only)

    char* p = (char*)d_ws;
    auto alloc = [&](size_t bytes) {
        char* r = p;
        p += (bytes + 63) & ~(size_t)63;
        return r;
    };
    int* deg        = (int*)alloc(NNODES * 4);
    int* epos       = (int*)alloc(NEDGES * 4);
    int* row_ptr    = (int*)alloc((NNODES + 1) * 4);
    int* bsum       = (int*)alloc(256 * 4);
    int* bofs       = (int*)alloc(256 * 4);
    int* sorted_src = (int*)alloc(NEDGES * 4);
    float* normb    = (float*)alloc(NNODES * 4);
    unsigned short* wT = (unsigned short*)alloc((size_t)32768 * 2);   // w_in hi/lo
    _Float16* w1f   = (_Float16*)alloc((size_t)6 * 16384 * 2);
    _Float16* w2f   = (_Float16*)alloc((size_t)6 * 16384 * 2);
    _Float16* woutf = (_Float16*)alloc((size_t)8192 * 2);
    unsigned short* xc_x = (unsigned short*)alloc((size_t)NPAD * 256 * 2);
    unsigned short* xc_in = (unsigned short*)alloc((size_t)NPAD * 256 * 2);
    _Float16* yA    = (_Float16*)alloc((size_t)NPAD * 128 * 2);
    _Float16* yB    = (_Float16*)alloc((size_t)NPAD * 128 * 2);

    // ---- CSR + norm + weight prep ----
    hipMemsetAsync(deg, 0, NNODES * sizeof(int), stream);
    count_kernel<<<(NEDGES + 255) / 256, 256, 0, stream>>>(dst, deg, epos);
    bsum_kernel<<<196, 256, 0, stream>>>(deg, bsum);
    bscan_kernel<<<1, 256, 0, stream>>>(bsum, bofs);
    emit_kernel<<<196, 256, 0, stream>>>(deg, bofs, row_ptr, normb);
    fill_kernel<<<(NEDGES + 255) / 256, 256, 0, stream>>>(src, dst, epos, row_ptr, sorted_src);
    prep_w_kernel<<<864, 256, 0, stream>>>(w_in, w1, w2, w_out, wT, w1f, w2f, woutf);

    // input layer: y0 = (inputs @ w_in)*norm (hi/lo, full precision A and B)
    split_x_kernel<<<(NPAD * 64) / 256, 256, 0, stream>>>(inputs, xc_in);
    gemm_bf_kernel<128><<<GEMM_GRID, GEMM_BLK, 0, stream>>>(xc_in, wT, normb, yA);

    // x1 = leaky(agg(y0)+b_in) -> xc_x state; fused with w1_0 GEMM -> yB
    fga_kernel<0, 128, true, false><<<GEMM_GRID, GEMM_BLK, 0, stream>>>(
        yA, row_ptr, sorted_src, normb, b_in, nullptr, w1f, xc_x, nullptr, yB);

    // 6 residual blocks: two fused kernels each
    for (int i = 0; i < 6; ++i) {
        // h = leaky(agg(yB)+b1_i); yA = (h @ w2_i)*norm
        fga_kernel<0, 128, false, false><<<GEMM_GRID, GEMM_BLK, 0, stream>>>(
            yB, row_ptr, sorted_src, normb, b1 + i * HDIM, nullptr,
            w2f + (size_t)i * 16384, nullptr, nullptr, yA);
        if (i < 5)
            // x = (x + leaky(agg(yA)+b2_i))/2 -> xc_x; yB = (x @ w1_{i+1})*norm
            fga_kernel<1, 128, true, false><<<GEMM_GRID, GEMM_BLK, 0, stream>>>(
                yA, row_ptr, sorted_src, normb, b2 + i * HDIM, xc_x,
                w1f + (size_t)(i + 1) * 16384, xc_x, nullptr, yB);
        else
            // final block: x -> fp32 out; yB = (x @ w_out)*norm (64 cols)
            fga_kernel<1, 64, false, true><<<GEMM_GRID, GEMM_BLK, 0, stream>>>(
                yA, row_ptr, sorted_src, normb, b2 + i * HDIM, xc_x,
                woutf, nullptr, x, yB);
    }

    // final aggregation (identity conv epilogue, 64 cols)
    gather_fin64<<<NNODES / 16, 256, 0, stream>>>(
        yB, row_ptr, sorted_src, normb, b_out, xout);
}